// Round 1
// baseline (624.964 us; speedup 1.0000x reference)
//
#include <hip/hip_runtime.h>
#include <math.h>

#define BS   16
#define NA   8400
#define NGT  64
#define NC   80
#define TK   13
#define EPSA 1e-9f     // assigner EPS
#define EPSC 1e-7f     // ciou eps

// ---------------- K1: metrics ----------------
// block = one (b, j) gt row; threads stride anchors.
__global__ void k1_metrics(const float* __restrict__ pd_scores,
                           const float* __restrict__ pd_bboxes,
                           const float* __restrict__ anc,
                           const int*   __restrict__ gt_labels,
                           const float* __restrict__ gt_bboxes,
                           const float* __restrict__ mask_gt,
                           float* __restrict__ align_m,
                           float* __restrict__ ovl,
                           unsigned char* __restrict__ maskc) {
    int bj = blockIdx.x;            // b*NGT + j
    int b  = bj / NGT;
    float4 g   = ((const float4*)gt_bboxes)[bj];
    int    lbl = gt_labels[bj];
    float  mgt = mask_gt[bj];
    float w1  = g.z - g.x;
    float h1  = g.w - g.y + EPSC;
    float at1 = atanf(w1 / h1);
    float a1  = w1 * h1;
    size_t rowoff = (size_t)bj * NA;
    const float*  psc = pd_scores + (size_t)b * NA * NC + lbl;
    const float4* pbb = ((const float4*)pd_bboxes) + (size_t)b * NA;

    for (int a = threadIdx.x; a < NA; a += blockDim.x) {
        float2 ap = ((const float2*)anc)[a];
        float4 p  = pbb[a];
        float dmin = fminf(fminf(ap.x - g.x, ap.y - g.y),
                           fminf(g.z - ap.x, g.w - ap.y));
        bool m = (dmin > EPSA) && (mgt > 0.f);
        float o = 0.f, al = 0.f;
        if (m) {
            float w2 = p.z - p.x;
            float h2 = p.w - p.y + EPSC;
            float iw = fminf(g.z, p.z) - fmaxf(g.x, p.x);
            float ih = fminf(g.w, p.w) - fmaxf(g.y, p.y);
            float inter = fmaxf(iw, 0.f) * fmaxf(ih, 0.f);
            float uni   = a1 + w2 * h2 - inter + EPSC;
            float iou   = inter / uni;
            float cw = fmaxf(g.z, p.z) - fminf(g.x, p.x);
            float ch = fmaxf(g.w, p.w) - fminf(g.y, p.y);
            float c2 = cw * cw + ch * ch + EPSC;
            float dx = p.x + p.z - g.x - g.z;
            float dy = p.y + p.w - g.y - g.w;
            float rho2 = (dx * dx + dy * dy) * 0.25f;
            float dat  = atanf(w2 / h2) - at1;
            float v    = (4.0f / (float)(M_PI * M_PI)) * dat * dat;
            float alpha = v / (v - iou + (1.0f + EPSC));
            float ciou  = iou - (rho2 / c2 + v * alpha);
            o = fmaxf(ciou, 0.f);
            float sc = psc[(size_t)a * NC];
            float o2 = o * o;
            al = sc * (o2 * o2 * o2);   // score^1 * ovl^6
        }
        align_m[rowoff + a] = al;
        ovl[rowoff + a]     = o;
        maskc[rowoff + a]   = m ? (unsigned char)1 : (unsigned char)0;
    }
}

// ---------------- K2: top-13 per (b,j) ----------------
// 13 passes of block argmax with (value desc, index asc) tie-break,
// excluding already-chosen indices. Matches jax.lax.top_k ordering.
__global__ void k2_topk(const float* __restrict__ align_m,
                        const unsigned char* __restrict__ maskc,
                        const float* __restrict__ mask_gt,
                        unsigned char* __restrict__ maskp) {
    int bj = blockIdx.x;
    if (mask_gt[bj] <= 0.f) return;   // row stays all-zero (count>1 at idx0 in ref)
    const float* row = align_m + (size_t)bj * NA;
    __shared__ float sval[256];
    __shared__ int   sidx[256];
    __shared__ int   chosen[TK];
    int tid = threadIdx.x;
    for (int it = 0; it < TK; ++it) {
        float bv = -1.f; int bi = NA;
        for (int a = tid; a < NA; a += 256) {
            bool skip = false;
            for (int c = 0; c < it; ++c)
                if (chosen[c] == a) { skip = true; break; }
            if (skip) continue;
            float v = row[a];
            if (v > bv) { bv = v; bi = a; }   // ascending scan -> lowest idx kept on ties
        }
        sval[tid] = bv; sidx[tid] = bi;
        __syncthreads();
        for (int s = 128; s > 0; s >>= 1) {
            if (tid < s) {
                float v2 = sval[tid + s]; int i2 = sidx[tid + s];
                if (v2 > sval[tid] || (v2 == sval[tid] && i2 < sidx[tid])) {
                    sval[tid] = v2; sidx[tid] = i2;
                }
            }
            __syncthreads();
        }
        if (tid == 0) chosen[it] = sidx[0];
        __syncthreads();
    }
    if (tid < TK) {
        int a = chosen[tid];
        size_t off = (size_t)bj * NA + a;
        if (maskc[off]) maskp[off] = 1;   // mask_pos = topk & in_gts & mask_gt
    }
}

// ---------------- K3: resolve multi-assignment, write labels/bboxes/fg/idx ----
__global__ void k3_resolve(const float* __restrict__ ovl,
                           const int*   __restrict__ gt_labels,
                           const float* __restrict__ gt_bboxes,
                           unsigned char* __restrict__ maskp,
                           float* __restrict__ out_labels,
                           float* __restrict__ out_bboxes,
                           float* __restrict__ out_fg,
                           float* __restrict__ out_tgt,
                           int* __restrict__ fg_i,
                           int* __restrict__ tgt_i) {
    int i = blockIdx.x * blockDim.x + threadIdx.x;   // b*NA + a
    if (i >= BS * NA) return;
    int b = i / NA, a = i - b * NA;
    size_t base = (size_t)b * NGT * NA + a;
    int fg = 0, first = -1;
    for (int j = 0; j < NGT; ++j) {
        if (maskp[base + (size_t)j * NA]) { fg++; if (first < 0) first = j; }
    }
    int tgt;
    if (fg > 1) {
        // argmax over ALL gts of overlaps column; first max wins
        float bv = ovl[base]; int bj2 = 0;
        for (int j = 1; j < NGT; ++j) {
            float v = ovl[base + (size_t)j * NA];
            if (v > bv) { bv = v; bj2 = j; }
        }
        for (int j = 0; j < NGT; ++j)
            maskp[base + (size_t)j * NA] = (j == bj2) ? 1 : 0;
        tgt = bj2; fg = 1;
    } else {
        tgt = (fg > 0) ? first : 0;
    }
    int lbl = gt_labels[b * NGT + tgt]; if (lbl < 0) lbl = 0;
    float4 gb = ((const float4*)gt_bboxes)[b * NGT + tgt];
    out_labels[i] = (float)lbl;
    ((float4*)out_bboxes)[i] = gb;
    out_fg[i]  = (fg > 0) ? 1.f : 0.f;
    out_tgt[i] = (float)tgt;
    fg_i[i]  = fg;
    tgt_i[i] = tgt;
}

// ---------------- K4: per-(b,j) max of align*maskp and ovl*maskp ----------------
__global__ void k4_rowmax(const float* __restrict__ align_m,
                          const float* __restrict__ ovl,
                          const unsigned char* __restrict__ maskp,
                          float* __restrict__ pos_align,
                          float* __restrict__ pos_ov) {
    int bj = blockIdx.x;
    size_t off = (size_t)bj * NA;
    float ma = 0.f, mo = 0.f;
    for (int a = threadIdx.x; a < NA; a += 256) {
        if (maskp[off + a]) {
            ma = fmaxf(ma, align_m[off + a]);
            mo = fmaxf(mo, ovl[off + a]);
        }
    }
    __shared__ float sa[256], so[256];
    sa[threadIdx.x] = ma; so[threadIdx.x] = mo;
    __syncthreads();
    for (int s = 128; s > 0; s >>= 1) {
        if (threadIdx.x < s) {
            sa[threadIdx.x] = fmaxf(sa[threadIdx.x], sa[threadIdx.x + s]);
            so[threadIdx.x] = fmaxf(so[threadIdx.x], so[threadIdx.x + s]);
        }
        __syncthreads();
    }
    if (threadIdx.x == 0) { pos_align[bj] = sa[0]; pos_ov[bj] = so[0]; }
}

// ---------------- K5a: norm per (b,a) ----------------
__global__ void k5a_norm(const float* __restrict__ align_m,
                         const unsigned char* __restrict__ maskp,
                         const float* __restrict__ pos_align,
                         const float* __restrict__ pos_ov,
                         float* __restrict__ norm) {
    int i = blockIdx.x * blockDim.x + threadIdx.x;
    if (i >= BS * NA) return;
    int b = i / NA, a = i - b * NA;
    size_t base = (size_t)b * NGT * NA + a;
    float nm = 0.f;
    for (int j = 0; j < NGT; ++j) {
        if (maskp[base + (size_t)j * NA]) {
            int bj = b * NGT + j;
            float m = align_m[base + (size_t)j * NA] * pos_ov[bj] / (pos_align[bj] + EPSA);
            nm = fmaxf(nm, m);
        }
    }
    norm[i] = nm;
}

// ---------------- K5b: one-hot scores * norm (coalesced) ----------------
__global__ void k5b_scores(const float* __restrict__ norm,
                           const int* __restrict__ tgt_i,
                           const int* __restrict__ fg_i,
                           const int* __restrict__ gt_labels,
                           float* __restrict__ out_scores) {
    size_t i = (size_t)blockIdx.x * blockDim.x + threadIdx.x;  // b*NA*NC + a*NC + c
    if (i >= (size_t)BS * NA * NC) return;
    int c  = (int)(i % NC);
    int ba = (int)(i / NC);
    float val = 0.f;
    if (fg_i[ba] > 0) {
        int b = ba / NA;
        int lbl = gt_labels[b * NGT + tgt_i[ba]];
        if (lbl < 0) lbl = 0;
        if (c == lbl) val = norm[ba];
    }
    out_scores[i] = val;
}

extern "C" void kernel_launch(void* const* d_in, const int* in_sizes, int n_in,
                              void* d_out, int out_size, void* d_ws, size_t ws_size,
                              hipStream_t stream) {
    const float* pd_scores = (const float*)d_in[0];
    const float* pd_bboxes = (const float*)d_in[1];
    const float* anc       = (const float*)d_in[2];
    const int*   gt_labels = (const int*)d_in[3];
    const float* gt_bboxes = (const float*)d_in[4];
    const float* mask_gt   = (const float*)d_in[5];

    // ---- workspace carve ----
    const size_t RC = (size_t)BS * NGT * NA;   // 8,601,600
    char* p = (char*)d_ws;
    float* align_m   = (float*)p; p += RC * sizeof(float);
    float* ovl       = (float*)p; p += RC * sizeof(float);
    float* pos_align = (float*)p; p += (size_t)BS * NGT * sizeof(float);
    float* pos_ov    = (float*)p; p += (size_t)BS * NGT * sizeof(float);
    float* norm      = (float*)p; p += (size_t)BS * NA * sizeof(float);
    int*   fg_i      = (int*)p;   p += (size_t)BS * NA * sizeof(int);
    int*   tgt_i     = (int*)p;   p += (size_t)BS * NA * sizeof(int);
    unsigned char* maskc = (unsigned char*)p; p += RC;
    unsigned char* maskp = (unsigned char*)p; p += RC;

    // ---- output carve (all float32, concatenated in return order) ----
    float* out_labels = (float*)d_out;                       // BS*NA
    float* out_bboxes = out_labels + (size_t)BS * NA;        // BS*NA*4
    float* out_scores = out_bboxes + (size_t)BS * NA * 4;    // BS*NA*NC
    float* out_fg     = out_scores + (size_t)BS * NA * NC;   // BS*NA
    float* out_tgt    = out_fg     + (size_t)BS * NA;        // BS*NA

    hipMemsetAsync(maskp, 0, RC, stream);

    dim3 blk(256);
    k1_metrics<<<BS * NGT, blk, 0, stream>>>(pd_scores, pd_bboxes, anc, gt_labels,
                                             gt_bboxes, mask_gt, align_m, ovl, maskc);
    k2_topk<<<BS * NGT, blk, 0, stream>>>(align_m, maskc, mask_gt, maskp);
    k3_resolve<<<(BS * NA + 255) / 256, blk, 0, stream>>>(ovl, gt_labels, gt_bboxes, maskp,
                                                          out_labels, out_bboxes, out_fg,
                                                          out_tgt, fg_i, tgt_i);
    k4_rowmax<<<BS * NGT, blk, 0, stream>>>(align_m, ovl, maskp, pos_align, pos_ov);
    k5a_norm<<<(BS * NA + 255) / 256, blk, 0, stream>>>(align_m, maskp, pos_align, pos_ov, norm);
    k5b_scores<<<(int)(((size_t)BS * NA * NC + 255) / 256), blk, 0, stream>>>(
        norm, tgt_i, fg_i, gt_labels, out_scores);
}

// Round 2
// 138.537 us; speedup vs baseline: 4.5112x; 4.5112x over previous
//
#include <hip/hip_runtime.h>
#include <math.h>

#define BS   16
#define NA   8400
#define NGT  64
#define NC   80
#define TK   13
#define EPSA 1e-9f     // assigner EPS
#define EPSC 1e-7f     // ciou eps

typedef unsigned long long u64;

__device__ __forceinline__ u64 umax64(u64 a, u64 b) { return a > b ? a : b; }
__device__ __forceinline__ u64 umin64(u64 a, u64 b) { return a < b ? a : b; }

__device__ __forceinline__ u64 shfl_xor_u64(u64 v, int m) {
    int lo = __shfl_xor((int)(unsigned)v, m, 64);
    int hi = __shfl_xor((int)(unsigned)(v >> 32), m, 64);
    return ((u64)(unsigned)hi << 32) | (unsigned)lo;
}

// Merge two desc-sorted 16-lists (tail entries may be sentinels), keep top-16 desc in t.
// Bitonic: partner-select c[i]=max(t[i], o[15-i]) yields top-16 multiset as a bitonic
// sequence; 4-stage bitonic clean sorts it descending. All indices compile-time.
__device__ __forceinline__ void merge16(u64* t, const u64* o) {
    u64 c[16];
#pragma unroll
    for (int i = 0; i < 16; ++i) c[i] = umax64(t[i], o[15 - i]);
#pragma unroll
    for (int d = 8; d >= 1; d >>= 1) {
#pragma unroll
        for (int i = 0; i < 16; ++i) {
            if ((i & d) == 0) {
                u64 hi = umax64(c[i], c[i + d]);
                u64 lo = umin64(c[i], c[i + d]);
                c[i] = hi; c[i + d] = lo;
            }
        }
    }
#pragma unroll
    for (int i = 0; i < 16; ++i) t[i] = c[i];
}

// ---------------- K1 fused: metrics + single-pass top-13 ----------------
// block = one (b, j) gt row; threads stride anchors.
__global__ __launch_bounds__(256) void k1_fused(
        const float* __restrict__ pd_scores,
        const float* __restrict__ pd_bboxes,
        const float* __restrict__ anc,
        const int*   __restrict__ gt_labels,
        const float* __restrict__ gt_bboxes,
        const float* __restrict__ mask_gt,
        float* __restrict__ align_m,
        float* __restrict__ ovl,
        unsigned char* __restrict__ maskp) {
    int bj = blockIdx.x;            // b*NGT + j
    int b  = bj / NGT;
    float4 g   = ((const float4*)gt_bboxes)[bj];
    int    lbl = gt_labels[bj];
    float  mgt = mask_gt[bj];
    size_t rowoff = (size_t)bj * NA;
    bool active = (mgt > 0.f);

    if (!active) {
        // row contributes nothing downstream except ovl reads (must be 0)
        for (int a = threadIdx.x; a < NA; a += 256) {
            align_m[rowoff + a] = 0.f;
            ovl[rowoff + a]     = 0.f;
        }
        return;   // uniform across block: no barrier reached by anyone
    }

    float w1  = g.z - g.x;
    float h1  = g.w - g.y + EPSC;
    float at1 = atanf(w1 / h1);
    float a1  = w1 * h1;
    const float*  psc = pd_scores + (size_t)b * NA * NC + lbl;
    const float4* pbb = ((const float4*)pd_bboxes) + (size_t)b * NA;

    u64 t[16];
#pragma unroll
    for (int i = 0; i < 16; ++i) t[i] = 0;

    for (int a = threadIdx.x; a < NA; a += 256) {
        float2 ap = ((const float2*)anc)[a];
        float4 p  = pbb[a];
        float dmin = fminf(fminf(ap.x - g.x, ap.y - g.y),
                           fminf(g.z - ap.x, g.w - ap.y));
        bool m = (dmin > EPSA);
        float o = 0.f, al = 0.f;
        if (m) {
            float w2 = p.z - p.x;
            float h2 = p.w - p.y + EPSC;
            float iw = fminf(g.z, p.z) - fmaxf(g.x, p.x);
            float ih = fminf(g.w, p.w) - fmaxf(g.y, p.y);
            float inter = fmaxf(iw, 0.f) * fmaxf(ih, 0.f);
            float uni   = a1 + w2 * h2 - inter + EPSC;
            float iou   = inter / uni;
            float cw = fmaxf(g.z, p.z) - fminf(g.x, p.x);
            float ch = fmaxf(g.w, p.w) - fminf(g.y, p.y);
            float c2 = cw * cw + ch * ch + EPSC;
            float dx = p.x + p.z - g.x - g.z;
            float dy = p.y + p.w - g.y - g.w;
            float rho2 = (dx * dx + dy * dy) * 0.25f;
            float dat  = atanf(w2 / h2) - at1;
            float v    = (4.0f / (float)(M_PI * M_PI)) * dat * dat;
            float alpha = v / (v - iou + (1.0f + EPSC));
            float ciou  = iou - (rho2 / c2 + v * alpha);
            o = fmaxf(ciou, 0.f);
            float sc = psc[(size_t)a * NC];
            float o2 = o * o;
            al = sc * (o2 * o2 * o2);   // score^1 * ovl^6
        }
        align_m[rowoff + a] = al;
        ovl[rowoff + a]     = o;
        // key: value desc, then index asc (16384-a desc), mask bit in LSB (free ride)
        u64 key = ((u64)__float_as_uint(al) << 32) |
                  (u64)(((unsigned)(16384 - a) << 1) | (m ? 1u : 0u));
        // branch-free sorted insert into t[0..12]; t[13..15] stay sentinels here
        u64 cur = key;
#pragma unroll
        for (int s = 0; s < 13; ++s) {
            u64 hi = umax64(t[s], cur);
            cur    = umin64(t[s], cur);
            t[s]   = hi;
        }
    }

    // wave butterfly merge (all lanes converge to wave top-13)
#pragma unroll
    for (int d = 1; d < 64; d <<= 1) {
        u64 o16[16];
#pragma unroll
        for (int i = 0; i < 13; ++i) o16[i] = shfl_xor_u64(t[i], d);
#pragma unroll
        for (int i = 13; i < 16; ++i) o16[i] = 0;
        merge16(t, o16);
    }

    // cross-wave merge via LDS
    __shared__ u64 sbuf[4][16];
    if ((threadIdx.x & 63) == 0) {
        int w = threadIdx.x >> 6;
#pragma unroll
        for (int i = 0; i < 16; ++i) sbuf[w][i] = t[i];
    }
    __syncthreads();
    if (threadIdx.x == 0) {
        for (int w2 = 1; w2 < 4; ++w2) merge16(t, sbuf[w2]);
#pragma unroll
        for (int it = 0; it < TK; ++it) {
            unsigned low = (unsigned)t[it];
            int a = 16384 - (int)(low >> 1);
            if (low & 1u) maskp[rowoff + a] = 1;   // topk & in_gts (& mask_gt via active)
        }
    }
}

// ---------------- K3: resolve multi-assignment, write labels/bboxes/fg/idx ----
__global__ void k3_resolve(const float* __restrict__ ovl,
                           const int*   __restrict__ gt_labels,
                           const float* __restrict__ gt_bboxes,
                           unsigned char* __restrict__ maskp,
                           float* __restrict__ out_labels,
                           float* __restrict__ out_bboxes,
                           float* __restrict__ out_fg,
                           float* __restrict__ out_tgt,
                           int* __restrict__ fg_i,
                           int* __restrict__ tgt_i) {
    int i = blockIdx.x * blockDim.x + threadIdx.x;   // b*NA + a
    if (i >= BS * NA) return;
    int b = i / NA, a = i - b * NA;
    size_t base = (size_t)b * NGT * NA + a;
    int fg = 0, first = -1;
    for (int j = 0; j < NGT; ++j) {
        if (maskp[base + (size_t)j * NA]) { fg++; if (first < 0) first = j; }
    }
    int tgt;
    if (fg > 1) {
        float bv = ovl[base]; int bj2 = 0;
        for (int j = 1; j < NGT; ++j) {
            float v = ovl[base + (size_t)j * NA];
            if (v > bv) { bv = v; bj2 = j; }      // strict > : first max wins
        }
        for (int j = 0; j < NGT; ++j)
            maskp[base + (size_t)j * NA] = (j == bj2) ? 1 : 0;
        tgt = bj2; fg = 1;
    } else {
        tgt = (fg > 0) ? first : 0;
    }
    int lbl = gt_labels[b * NGT + tgt]; if (lbl < 0) lbl = 0;
    float4 gb = ((const float4*)gt_bboxes)[b * NGT + tgt];
    out_labels[i] = (float)lbl;
    ((float4*)out_bboxes)[i] = gb;
    out_fg[i]  = (fg > 0) ? 1.f : 0.f;
    out_tgt[i] = (float)tgt;
    fg_i[i]  = fg;
    tgt_i[i] = tgt;
}

// ---------------- K4: per-(b,j) max of align*maskp and ovl*maskp ----------------
__global__ void k4_rowmax(const float* __restrict__ align_m,
                          const float* __restrict__ ovl,
                          const unsigned char* __restrict__ maskp,
                          float* __restrict__ pos_align,
                          float* __restrict__ pos_ov) {
    int bj = blockIdx.x;
    size_t off = (size_t)bj * NA;
    float ma = 0.f, mo = 0.f;
    for (int a = threadIdx.x; a < NA; a += 256) {
        if (maskp[off + a]) {
            ma = fmaxf(ma, align_m[off + a]);
            mo = fmaxf(mo, ovl[off + a]);
        }
    }
    __shared__ float sa[256], so[256];
    sa[threadIdx.x] = ma; so[threadIdx.x] = mo;
    __syncthreads();
    for (int s = 128; s > 0; s >>= 1) {
        if (threadIdx.x < s) {
            sa[threadIdx.x] = fmaxf(sa[threadIdx.x], sa[threadIdx.x + s]);
            so[threadIdx.x] = fmaxf(so[threadIdx.x], so[threadIdx.x + s]);
        }
        __syncthreads();
    }
    if (threadIdx.x == 0) { pos_align[bj] = sa[0]; pos_ov[bj] = so[0]; }
}

// ---------------- K5a: norm per (b,a) ----------------
__global__ void k5a_norm(const float* __restrict__ align_m,
                         const unsigned char* __restrict__ maskp,
                         const float* __restrict__ pos_align,
                         const float* __restrict__ pos_ov,
                         float* __restrict__ norm) {
    int i = blockIdx.x * blockDim.x + threadIdx.x;
    if (i >= BS * NA) return;
    int b = i / NA, a = i - b * NA;
    size_t base = (size_t)b * NGT * NA + a;
    float nm = 0.f;
    for (int j = 0; j < NGT; ++j) {
        if (maskp[base + (size_t)j * NA]) {
            int bj = b * NGT + j;
            float m = align_m[base + (size_t)j * NA] * pos_ov[bj] / (pos_align[bj] + EPSA);
            nm = fmaxf(nm, m);
        }
    }
    norm[i] = nm;
}

// ---------------- K5b: one-hot scores * norm (coalesced) ----------------
__global__ void k5b_scores(const float* __restrict__ norm,
                           const int* __restrict__ tgt_i,
                           const int* __restrict__ fg_i,
                           const int* __restrict__ gt_labels,
                           float* __restrict__ out_scores) {
    size_t i = (size_t)blockIdx.x * blockDim.x + threadIdx.x;  // b*NA*NC + a*NC + c
    if (i >= (size_t)BS * NA * NC) return;
    int c  = (int)(i % NC);
    int ba = (int)(i / NC);
    float val = 0.f;
    if (fg_i[ba] > 0) {
        int b = ba / NA;
        int lbl = gt_labels[b * NGT + tgt_i[ba]];
        if (lbl < 0) lbl = 0;
        if (c == lbl) val = norm[ba];
    }
    out_scores[i] = val;
}

extern "C" void kernel_launch(void* const* d_in, const int* in_sizes, int n_in,
                              void* d_out, int out_size, void* d_ws, size_t ws_size,
                              hipStream_t stream) {
    const float* pd_scores = (const float*)d_in[0];
    const float* pd_bboxes = (const float*)d_in[1];
    const float* anc       = (const float*)d_in[2];
    const int*   gt_labels = (const int*)d_in[3];
    const float* gt_bboxes = (const float*)d_in[4];
    const float* mask_gt   = (const float*)d_in[5];

    // ---- workspace carve ----
    const size_t RC = (size_t)BS * NGT * NA;   // 8,601,600
    char* p = (char*)d_ws;
    float* align_m   = (float*)p; p += RC * sizeof(float);
    float* ovl       = (float*)p; p += RC * sizeof(float);
    float* pos_align = (float*)p; p += (size_t)BS * NGT * sizeof(float);
    float* pos_ov    = (float*)p; p += (size_t)BS * NGT * sizeof(float);
    float* norm      = (float*)p; p += (size_t)BS * NA * sizeof(float);
    int*   fg_i      = (int*)p;   p += (size_t)BS * NA * sizeof(int);
    int*   tgt_i     = (int*)p;   p += (size_t)BS * NA * sizeof(int);
    unsigned char* maskp = (unsigned char*)p; p += RC;

    // ---- output carve (all float32, concatenated in return order) ----
    float* out_labels = (float*)d_out;                       // BS*NA
    float* out_bboxes = out_labels + (size_t)BS * NA;        // BS*NA*4
    float* out_scores = out_bboxes + (size_t)BS * NA * 4;    // BS*NA*NC
    float* out_fg     = out_scores + (size_t)BS * NA * NC;   // BS*NA
    float* out_tgt    = out_fg     + (size_t)BS * NA;        // BS*NA

    hipMemsetAsync(maskp, 0, RC, stream);

    dim3 blk(256);
    k1_fused<<<BS * NGT, blk, 0, stream>>>(pd_scores, pd_bboxes, anc, gt_labels,
                                           gt_bboxes, mask_gt, align_m, ovl, maskp);
    k3_resolve<<<(BS * NA + 255) / 256, blk, 0, stream>>>(ovl, gt_labels, gt_bboxes, maskp,
                                                          out_labels, out_bboxes, out_fg,
                                                          out_tgt, fg_i, tgt_i);
    k4_rowmax<<<BS * NGT, blk, 0, stream>>>(align_m, ovl, maskp, pos_align, pos_ov);
    k5a_norm<<<(BS * NA + 255) / 256, blk, 0, stream>>>(align_m, maskp, pos_align, pos_ov, norm);
    k5b_scores<<<(int)(((size_t)BS * NA * NC + 255) / 256), blk, 0, stream>>>(
        norm, tgt_i, fg_i, gt_labels, out_scores);
}

// Round 3
// 132.568 us; speedup vs baseline: 4.7143x; 1.0450x over previous
//
#include <hip/hip_runtime.h>
#include <math.h>

#define BS   16
#define NA   8400
#define NGT  64
#define NC   80
#define TK   13
#define EPSA 1e-9f     // assigner EPS
#define EPSC 1e-7f     // ciou eps

typedef unsigned long long u64;

__device__ __forceinline__ u64 umax64(u64 a, u64 b) { return a > b ? a : b; }
__device__ __forceinline__ u64 umin64(u64 a, u64 b) { return a < b ? a : b; }

__device__ __forceinline__ u64 shfl_xor_u64(u64 v, int m) {
    int lo = __shfl_xor((int)(unsigned)v, m, 64);
    int hi = __shfl_xor((int)(unsigned)(v >> 32), m, 64);
    return ((u64)(unsigned)hi << 32) | (unsigned)lo;
}

// Merge two desc-sorted 16-lists, keep top-16 desc in t. Exact (bitonic).
__device__ __forceinline__ void merge16(u64* t, const u64* o) {
    u64 c[16];
#pragma unroll
    for (int i = 0; i < 16; ++i) c[i] = umax64(t[i], o[15 - i]);
#pragma unroll
    for (int d = 8; d >= 1; d >>= 1) {
#pragma unroll
        for (int i = 0; i < 16; ++i) {
            if ((i & d) == 0) {
                u64 hi = umax64(c[i], c[i + d]);
                u64 lo = umin64(c[i], c[i + d]);
                c[i] = hi; c[i + d] = lo;
            }
        }
    }
#pragma unroll
    for (int i = 0; i < 16; ++i) t[i] = c[i];
}

// branch-free sorted insert into t[0..12] (desc); t[13..15] untouched sentinels
__device__ __forceinline__ void insert13(u64* t, u64 key) {
    u64 cur = key;
#pragma unroll
    for (int s = 0; s < 13; ++s) {
        u64 hi = umax64(t[s], cur);
        cur    = umin64(t[s], cur);
        t[s]   = hi;
    }
}

// ---------------- K1: compact inside-anchors, CIoU on candidates, top-13 ----
// block = one (b, j) gt row; 512 threads.
// Candidate set = {inside anchors} U {a<16 outside (zero fillers)} provably
// contains the exact top-13 (any zero-value a>=16 is beaten by all 16 a<16 keys).
__global__ __launch_bounds__(512) void k1_fused(
        const float* __restrict__ pd_scores,
        const float* __restrict__ pd_bboxes,
        const float* __restrict__ anc,
        const int*   __restrict__ gt_labels,
        const float* __restrict__ gt_bboxes,
        const float* __restrict__ mask_gt,
        float* __restrict__ ovl,
        u64*   __restrict__ bits) {          // per (b,a): bitmask over j
    int bj = blockIdx.x;
    int b  = bj >> 6;
    int j  = bj & 63;
    float4 g   = ((const float4*)gt_bboxes)[bj];
    float  mgt = mask_gt[bj];
    size_t rowoff = (size_t)bj * NA;
    int tid = threadIdx.x;

    if (mgt <= 0.f) {                        // inactive row: ovl must read 0
        for (int a = tid; a < NA; a += 512) ovl[rowoff + a] = 0.f;
        return;                              // block-uniform exit
    }

    __shared__ int cnt;
    __shared__ int list[NA];
    __shared__ u64 sbuf[8][16];
    if (tid == 0) cnt = 0;
    __syncthreads();

    u64 t[16];
#pragma unroll
    for (int i = 0; i < 16; ++i) t[i] = 0;

    // ---- phase A: point-in-box test only (no pd_bboxes load) ----
    for (int a = tid; a < NA; a += 512) {
        float2 ap = ((const float2*)anc)[a];
        float dmin = fminf(fminf(ap.x - g.x, ap.y - g.y),
                           fminf(g.z - ap.x, g.w - ap.y));
        if (dmin > EPSA) {
            int p = atomicAdd(&cnt, 1);
            list[p] = a;
        } else {
            ovl[rowoff + a] = 0.f;
            if (a < 16) {   // zero filler: value 0, index-ordered, m=0
                u64 key = (u64)((unsigned)(16384 - a) << 1);
                insert13(t, key);
            }
        }
    }
    __syncthreads();
    int n = cnt;

    // ---- phase B: CIoU + align on compacted candidates ----
    float w1  = g.z - g.x;
    float h1  = g.w - g.y + EPSC;
    float at1 = atanf(w1 / h1);
    float a1  = w1 * h1;
    int   lbl = gt_labels[bj];
    const float*  psc = pd_scores + (size_t)b * NA * NC + lbl;
    const float4* pbb = ((const float4*)pd_bboxes) + (size_t)b * NA;

    for (int i = tid; i < n; i += 512) {
        int a = list[i];
        float4 p = pbb[a];
        float w2 = p.z - p.x;
        float h2 = p.w - p.y + EPSC;
        float iw = fminf(g.z, p.z) - fmaxf(g.x, p.x);
        float ih = fminf(g.w, p.w) - fmaxf(g.y, p.y);
        float inter = fmaxf(iw, 0.f) * fmaxf(ih, 0.f);
        float uni   = a1 + w2 * h2 - inter + EPSC;
        float iou   = inter / uni;
        float cw = fmaxf(g.z, p.z) - fminf(g.x, p.x);
        float ch = fmaxf(g.w, p.w) - fminf(g.y, p.y);
        float c2 = cw * cw + ch * ch + EPSC;
        float dx = p.x + p.z - g.x - g.z;
        float dy = p.y + p.w - g.y - g.w;
        float rho2 = (dx * dx + dy * dy) * 0.25f;
        float dat  = atanf(w2 / h2) - at1;
        float v    = (4.0f / (float)(M_PI * M_PI)) * dat * dat;
        float alpha = v / (v - iou + (1.0f + EPSC));
        float ciou  = iou - (rho2 / c2 + v * alpha);
        float o = fmaxf(ciou, 0.f);
        ovl[rowoff + a] = o;
        float sc = psc[(size_t)a * NC];
        float o2 = o * o;
        float al = sc * (o2 * o2 * o2);      // score^1 * ovl^6
        u64 key = ((u64)__float_as_uint(al) << 32) |
                  (u64)(((unsigned)(16384 - a) << 1) | 1u);
        insert13(t, key);
    }

    // ---- wave butterfly merge ----
#pragma unroll
    for (int d = 1; d < 64; d <<= 1) {
        u64 o16[16];
#pragma unroll
        for (int i = 0; i < 16; ++i) o16[i] = shfl_xor_u64(t[i], d);
        merge16(t, o16);
    }

    // ---- cross-wave tree merge ----
    int wid = tid >> 6;
    if ((tid & 63) == 0) {
#pragma unroll
        for (int i = 0; i < 16; ++i) sbuf[wid][i] = t[i];
    }
    __syncthreads();
    if (tid < 4) {
        u64 A[16], B[16];
#pragma unroll
        for (int i = 0; i < 16; ++i) { A[i] = sbuf[2*tid][i]; B[i] = sbuf[2*tid+1][i]; }
        merge16(A, B);
#pragma unroll
        for (int i = 0; i < 16; ++i) sbuf[2*tid][i] = A[i];
    }
    __syncthreads();
    if (tid < 2) {
        u64 A[16], B[16];
#pragma unroll
        for (int i = 0; i < 16; ++i) { A[i] = sbuf[4*tid][i]; B[i] = sbuf[4*tid+2][i]; }
        merge16(A, B);
#pragma unroll
        for (int i = 0; i < 16; ++i) sbuf[4*tid][i] = A[i];
    }
    __syncthreads();
    if (tid == 0) {
        u64 A[16], B[16];
#pragma unroll
        for (int i = 0; i < 16; ++i) { A[i] = sbuf[0][i]; B[i] = sbuf[4][i]; }
        merge16(A, B);
        u64 mybit = 1ULL << j;
#pragma unroll
        for (int it = 0; it < TK; ++it) {
            unsigned low = (unsigned)A[it];
            int a = 16384 - (int)(low >> 1);
            if (low & 1u)                     // in_gts bit: topk & in_gts & mask_gt
                atomicOr(&bits[(size_t)b * NA + a], mybit);
        }
    }
}

// ---------------- K3: resolve multi-assignment (per anchor) ----------------
__global__ void k3_resolve(const float* __restrict__ ovl,
                           const int*   __restrict__ gt_labels,
                           const float* __restrict__ gt_bboxes,
                           u64* __restrict__ bits,
                           float* __restrict__ out_labels,
                           float* __restrict__ out_bboxes,
                           float* __restrict__ out_fg,
                           float* __restrict__ out_tgt) {
    int i = blockIdx.x * blockDim.x + threadIdx.x;   // b*NA + a
    if (i >= BS * NA) return;
    int b = i / NA, a = i - b * NA;
    u64 mb = bits[i];
    int fg = __popcll(mb);
    int tgt;
    if (fg > 1) {
        // argmax over ALL gts of overlaps column; first max wins (strict >)
        const float* col = ovl + (size_t)b * NGT * NA + a;
        float bv = col[0]; int bj2 = 0;
        for (int jj = 1; jj < NGT; ++jj) {
            float v = col[(size_t)jj * NA];
            if (v > bv) { bv = v; bj2 = jj; }
        }
        bits[i] = 1ULL << bj2;
        tgt = bj2; fg = 1;
    } else {
        tgt = fg ? (__ffsll((long long)mb) - 1) : 0;
    }
    int lbl = gt_labels[b * NGT + tgt]; if (lbl < 0) lbl = 0;
    float4 gb = ((const float4*)gt_bboxes)[b * NGT + tgt];
    out_labels[i] = (float)lbl;
    ((float4*)out_bboxes)[i] = gb;
    out_fg[i]  = (fg > 0) ? 1.f : 0.f;
    out_tgt[i] = (float)tgt;
}

// ---------------- K4: per-(b,j) max of align and ovl over positives ----------
__global__ void k4_rowmax(const float* __restrict__ pd_scores,
                          const float* __restrict__ ovl,
                          const int*   __restrict__ gt_labels,
                          const u64*   __restrict__ bits,
                          float* __restrict__ pos_align,
                          float* __restrict__ pos_ov) {
    int bj = blockIdx.x;
    int b  = bj >> 6;
    int j  = bj & 63;
    int lbl = gt_labels[bj];
    const float* psc = pd_scores + (size_t)b * NA * NC + lbl;
    size_t off = (size_t)bj * NA;
    const u64* bp = bits + (size_t)b * NA;
    float ma = 0.f, mo = 0.f;
    for (int a = threadIdx.x; a < NA; a += 256) {
        if ((bp[a] >> j) & 1ULL) {
            float o  = ovl[off + a];
            float sc = psc[(size_t)a * NC];
            float o2 = o * o;
            float al = sc * (o2 * o2 * o2);   // same expr as k1 -> bit-identical
            ma = fmaxf(ma, al);
            mo = fmaxf(mo, o);
        }
    }
    __shared__ float sa[256], so[256];
    sa[threadIdx.x] = ma; so[threadIdx.x] = mo;
    __syncthreads();
    for (int s = 128; s > 0; s >>= 1) {
        if (threadIdx.x < s) {
            sa[threadIdx.x] = fmaxf(sa[threadIdx.x], sa[threadIdx.x + s]);
            so[threadIdx.x] = fmaxf(so[threadIdx.x], so[threadIdx.x + s]);
        }
        __syncthreads();
    }
    if (threadIdx.x == 0) { pos_align[bj] = sa[0]; pos_ov[bj] = so[0]; }
}

// ---------------- K5a: norm per (b,a) ----------------
__global__ void k5a_norm(const float* __restrict__ pd_scores,
                         const float* __restrict__ ovl,
                         const int*   __restrict__ gt_labels,
                         const u64*   __restrict__ bits,
                         const float* __restrict__ pos_align,
                         const float* __restrict__ pos_ov,
                         float* __restrict__ norm) {
    int i = blockIdx.x * blockDim.x + threadIdx.x;
    if (i >= BS * NA) return;
    int b = i / NA, a = i - b * NA;
    u64 mb = bits[i];                        // post-resolution: one-hot or 0
    float nm = 0.f;
    if (mb) {
        int j  = __ffsll((long long)mb) - 1;
        int bj = b * NGT + j;
        float o  = ovl[(size_t)bj * NA + a];
        int lbl  = gt_labels[bj];
        float sc = pd_scores[(size_t)b * NA * NC + (size_t)a * NC + lbl];
        float o2 = o * o;
        float al = sc * (o2 * o2 * o2);
        nm = al * pos_ov[bj] / (pos_align[bj] + EPSA);
    }
    norm[i] = nm;
}

// ---------------- K5b: one-hot scores * norm (float4 writes) ----------------
__global__ void k5b_scores(const float* __restrict__ norm,
                           const float* __restrict__ out_labels,
                           float* __restrict__ out_scores) {
    int i4 = blockIdx.x * blockDim.x + threadIdx.x;   // float4 index
    if (i4 >= BS * NA * NC / 4) return;
    int ba = i4 / 20;                 // 20 float4 per anchor (NC=80)
    int c0 = (i4 - ba * 20) * 4;
    float nm  = norm[ba];
    int   lbl = (int)out_labels[ba];  // clipped label; nm==0 for background
    float4 v = make_float4(0.f, 0.f, 0.f, 0.f);
    if (lbl >= c0 && lbl < c0 + 4) ((float*)&v)[lbl - c0] = nm;
    ((float4*)out_scores)[i4] = v;
}

extern "C" void kernel_launch(void* const* d_in, const int* in_sizes, int n_in,
                              void* d_out, int out_size, void* d_ws, size_t ws_size,
                              hipStream_t stream) {
    const float* pd_scores = (const float*)d_in[0];
    const float* pd_bboxes = (const float*)d_in[1];
    const float* anc       = (const float*)d_in[2];
    const int*   gt_labels = (const int*)d_in[3];
    const float* gt_bboxes = (const float*)d_in[4];
    const float* mask_gt   = (const float*)d_in[5];

    // ---- workspace carve ----
    const size_t RC = (size_t)BS * NGT * NA;   // 8,601,600
    char* p = (char*)d_ws;
    float* ovl       = (float*)p; p += RC * sizeof(float);
    u64*   bits      = (u64*)p;   p += (size_t)BS * NA * sizeof(u64);
    float* pos_align = (float*)p; p += (size_t)BS * NGT * sizeof(float);
    float* pos_ov    = (float*)p; p += (size_t)BS * NGT * sizeof(float);
    float* norm      = (float*)p; p += (size_t)BS * NA * sizeof(float);

    // ---- output carve (all float32, concatenated in return order) ----
    float* out_labels = (float*)d_out;                       // BS*NA
    float* out_bboxes = out_labels + (size_t)BS * NA;        // BS*NA*4
    float* out_scores = out_bboxes + (size_t)BS * NA * 4;    // BS*NA*NC
    float* out_fg     = out_scores + (size_t)BS * NA * NC;   // BS*NA
    float* out_tgt    = out_fg     + (size_t)BS * NA;        // BS*NA

    hipMemsetAsync(bits, 0, (size_t)BS * NA * sizeof(u64), stream);

    k1_fused<<<BS * NGT, 512, 0, stream>>>(pd_scores, pd_bboxes, anc, gt_labels,
                                           gt_bboxes, mask_gt, ovl, bits);
    k3_resolve<<<(BS * NA + 255) / 256, 256, 0, stream>>>(ovl, gt_labels, gt_bboxes, bits,
                                                          out_labels, out_bboxes,
                                                          out_fg, out_tgt);
    k4_rowmax<<<BS * NGT, 256, 0, stream>>>(pd_scores, ovl, gt_labels, bits,
                                            pos_align, pos_ov);
    k5a_norm<<<(BS * NA + 255) / 256, 256, 0, stream>>>(pd_scores, ovl, gt_labels, bits,
                                                        pos_align, pos_ov, norm);
    k5b_scores<<<(BS * NA * NC / 4 + 255) / 256, 256, 0, stream>>>(
        norm, out_labels, out_scores);
}

// Round 4
// 89.398 us; speedup vs baseline: 6.9908x; 1.4829x over previous
//
#include <hip/hip_runtime.h>
#include <math.h>

#define BS   16
#define NA   8400
#define NGT  64
#define NC   80
#define TK   13
#define CAP  1024               // per-(b,j) candidate list capacity (worst case ~450)
#define NCHUNK ((NA + 255) / 256)   // 33
#define EPSA 1e-9f
#define EPSC 1e-7f

typedef unsigned long long u64;

__device__ __forceinline__ u64 umax64(u64 a, u64 b) { return a > b ? a : b; }
__device__ __forceinline__ u64 umin64(u64 a, u64 b) { return a < b ? a : b; }

__device__ __forceinline__ u64 shfl_xor_u64(u64 v, int m) {
    int lo = __shfl_xor((int)(unsigned)v, m, 64);
    int hi = __shfl_xor((int)(unsigned)(v >> 32), m, 64);
    return ((u64)(unsigned)hi << 32) | (unsigned)lo;
}

// Merge two desc-sorted 16-lists, keep top-16 desc in t. Exact (bitonic).
__device__ __forceinline__ void merge16(u64* t, const u64* o) {
    u64 c[16];
#pragma unroll
    for (int i = 0; i < 16; ++i) c[i] = umax64(t[i], o[15 - i]);
#pragma unroll
    for (int d = 8; d >= 1; d >>= 1) {
#pragma unroll
        for (int i = 0; i < 16; ++i) {
            if ((i & d) == 0) {
                u64 hi = umax64(c[i], c[i + d]);
                u64 lo = umin64(c[i], c[i + d]);
                c[i] = hi; c[i + d] = lo;
            }
        }
    }
#pragma unroll
    for (int i = 0; i < 16; ++i) t[i] = c[i];
}

__device__ __forceinline__ void insert13(u64* t, u64 key) {
    u64 cur = key;
#pragma unroll
    for (int s = 0; s < 13; ++s) {
        u64 hi = umax64(t[s], cur);
        cur    = umin64(t[s], cur);
        t[s]   = hi;
    }
}

// identical expression in K1 and K3 -> bit-identical recompute
__device__ __forceinline__ float ciou_clip(float4 g, float4 p, float at1, float a1) {
    float w2 = p.z - p.x;
    float h2 = p.w - p.y + EPSC;
    float iw = fminf(g.z, p.z) - fmaxf(g.x, p.x);
    float ih = fminf(g.w, p.w) - fmaxf(g.y, p.y);
    float inter = fmaxf(iw, 0.f) * fmaxf(ih, 0.f);
    float uni   = a1 + w2 * h2 - inter + EPSC;
    float iou   = inter / uni;
    float cw = fmaxf(g.z, p.z) - fminf(g.x, p.x);
    float ch = fmaxf(g.w, p.w) - fminf(g.y, p.y);
    float c2 = cw * cw + ch * ch + EPSC;
    float dx = p.x + p.z - g.x - g.z;
    float dy = p.y + p.w - g.y - g.w;
    float rho2 = (dx * dx + dy * dy) * 0.25f;
    float dat  = atanf(w2 / h2) - at1;
    float v    = (4.0f / (float)(M_PI * M_PI)) * dat * dat;
    float alpha = v / (v - iou + (1.0f + EPSC));
    float ciou  = iou - (rho2 / c2 + v * alpha);
    return fmaxf(ciou, 0.f);
}

// ---------------- K1: anchor-centric pair scan ----------------
// thread = one (b,a). Loops 64 gts; pushes inside-pair keys to per-(b,j)
// candidate lists; tracks overlaps-argmax (first max) inline.
__global__ __launch_bounds__(256) void k1_pairs(
        const float* __restrict__ pd_scores,
        const float* __restrict__ pd_bboxes,
        const float* __restrict__ anc,
        const int*   __restrict__ gt_labels,
        const float* __restrict__ gt_bboxes,
        const float* __restrict__ mask_gt,
        u64* __restrict__ cand,
        int* __restrict__ cnt,
        unsigned char* __restrict__ amax_idx) {
    int bx = blockIdx.x;
    int b  = bx / NCHUNK;
    int a  = (bx % NCHUNK) * 256 + threadIdx.x;

    __shared__ float4 sg[NGT];
    __shared__ float  sat1[NGT], sa1[NGT], smgt[NGT];
    __shared__ int    slbl[NGT];
    if (threadIdx.x < NGT) {
        int j = threadIdx.x, bj = b * NGT + j;
        float4 g = ((const float4*)gt_bboxes)[bj];
        sg[j] = g;
        float w1 = g.z - g.x, h1 = g.w - g.y + EPSC;
        sat1[j] = atanf(w1 / h1);
        sa1[j]  = w1 * h1;
        smgt[j] = mask_gt[bj];
        slbl[j] = gt_labels[bj];
    }
    __syncthreads();
    if (a >= NA) return;

    float2 ap = ((const float2*)anc)[a];
    float4 p  = ((const float4*)pd_bboxes)[(size_t)b * NA + a];
    const float* sbase = pd_scores + (size_t)b * NA * NC + (size_t)a * NC;

    float bv = 0.f; int bi = 0;          // running argmax of overlaps (first max)
    for (int j = 0; j < NGT; ++j) {
        float4 g = sg[j];
        float dmin = fminf(fminf(ap.x - g.x, ap.y - g.y),
                           fminf(g.z - ap.x, g.w - ap.y));
        bool act    = smgt[j] > 0.f;
        bool inside = dmin > EPSA;
        float o = 0.f;
        if (act && inside) {
            o = ciou_clip(g, p, sat1[j], sa1[j]);
            float sc = sbase[slbl[j]];
            float o2 = o * o;
            float al = sc * (o2 * o2 * o2);      // score^1 * ovl^6
            u64 key = ((u64)__float_as_uint(al) << 32) |
                      (u64)(((unsigned)(16384 - a) << 1) | 1u);
            int bj = b * NGT + j;
            int pos = atomicAdd(&cnt[bj], 1);
            if (pos < CAP) cand[(size_t)bj * CAP + pos] = key;
        } else if (act && a < 16) {
            // zero filler: with inside a<16 entries these 16 smallest-index
            // candidates beat every outside a>=16 key -> exact top-13 coverage
            u64 key = (u64)((unsigned)(16384 - a) << 1);
            int bj = b * NGT + j;
            int pos = atomicAdd(&cnt[bj], 1);
            if (pos < CAP) cand[(size_t)bj * CAP + pos] = key;
        }
        if (o > bv) { bv = o; bi = j; }
    }
    amax_idx[(size_t)b * NA + a] = (unsigned char)bi;
}

// ---------------- K2: wave-per-row top-13 merge ----------------
__global__ __launch_bounds__(256) void k2_topk(
        const u64* __restrict__ cand,
        const int* __restrict__ cnt,
        u64* __restrict__ bits) {
    int bj   = blockIdx.x * 4 + (threadIdx.x >> 6);
    int lane = threadIdx.x & 63;
    int b = bj >> 6, j = bj & 63;
    int n = cnt[bj]; if (n > CAP) n = CAP;
    const u64* lst = cand + (size_t)bj * CAP;

    u64 t[16];
#pragma unroll
    for (int i = 0; i < 16; ++i) t[i] = 0;
    for (int i = lane; i < n; i += 64) insert13(t, lst[i]);

#pragma unroll
    for (int d = 1; d < 64; d <<= 1) {
        u64 o16[16];
#pragma unroll
        for (int i = 0; i < 16; ++i) o16[i] = shfl_xor_u64(t[i], d);
        merge16(t, o16);
    }
    if (lane == 0) {
        u64 mybit = 1ULL << j;
#pragma unroll
        for (int it = 0; it < TK; ++it) {
            unsigned low = (unsigned)t[it];
            int a = 16384 - (int)(low >> 1);
            if (low & 1u)
                atomicOr(&bits[(size_t)b * NA + a], mybit);
        }
    }
}

// ---------------- K3: per-anchor resolve + pos-maxes + outputs ----------------
__global__ __launch_bounds__(256) void k3_resolve(
        const float* __restrict__ pd_scores,
        const float* __restrict__ pd_bboxes,
        const float* __restrict__ anc,
        const int*   __restrict__ gt_labels,
        const float* __restrict__ gt_bboxes,
        const float* __restrict__ mask_gt,
        const u64* __restrict__ bits,
        const unsigned char* __restrict__ amax_idx,
        float* __restrict__ out_labels,
        float* __restrict__ out_bboxes,
        float* __restrict__ out_fg,
        float* __restrict__ out_tgt,
        float* __restrict__ al_res,
        unsigned* __restrict__ pos_align_u,
        unsigned* __restrict__ pos_ov_u) {
    int bx = blockIdx.x;
    int b  = bx / NCHUNK;
    int a  = (bx % NCHUNK) * 256 + threadIdx.x;

    __shared__ float4 sg[NGT];
    __shared__ float  sat1[NGT], sa1[NGT], smgt[NGT];
    __shared__ int    slbl[NGT];
    if (threadIdx.x < NGT) {
        int j = threadIdx.x, bj = b * NGT + j;
        float4 g = ((const float4*)gt_bboxes)[bj];
        sg[j] = g;
        float w1 = g.z - g.x, h1 = g.w - g.y + EPSC;
        sat1[j] = atanf(w1 / h1);
        sa1[j]  = w1 * h1;
        smgt[j] = mask_gt[bj];
        slbl[j] = gt_labels[bj];
    }
    __syncthreads();
    if (a >= NA) return;

    size_t i = (size_t)b * NA + a;
    u64 mb = bits[i];
    int fg = __popcll(mb);
    int tgt;
    if (fg > 1)      tgt = amax_idx[i];                       // is_max override
    else if (fg == 1) tgt = __ffsll((unsigned long long)mb) - 1;
    else             tgt = 0;

    float al = 0.f;
    if (fg > 0) {
        float4 g = sg[tgt];
        float2 ap = ((const float2*)anc)[a];
        float dmin = fminf(fminf(ap.x - g.x, ap.y - g.y),
                           fminf(g.z - ap.x, g.w - ap.y));
        if (smgt[tgt] > 0.f && dmin > EPSA) {
            float4 p = ((const float4*)pd_bboxes)[(size_t)b * NA + a];
            float o  = ciou_clip(g, p, sat1[tgt], sa1[tgt]);
            float sc = pd_scores[(size_t)b * NA * NC + (size_t)a * NC + slbl[tgt]];
            float o2 = o * o;
            al = sc * (o2 * o2 * o2);
            atomicMax(&pos_ov_u[b * NGT + tgt], __float_as_uint(o));
        }
        atomicMax(&pos_align_u[b * NGT + tgt], __float_as_uint(al));
    }
    al_res[i] = al;

    int lbl = slbl[tgt]; if (lbl < 0) lbl = 0;
    out_labels[i] = (float)lbl;
    ((float4*)out_bboxes)[i] = sg[tgt];
    out_fg[i]  = (fg > 0) ? 1.f : 0.f;
    out_tgt[i] = (float)tgt;
}

// ---------------- K5: fused norm + one-hot scores (float4 writes) ------------
__global__ __launch_bounds__(256) void k5_scores(
        const float* __restrict__ al_res,
        const float* __restrict__ out_labels,
        const float* __restrict__ out_fg,
        const float* __restrict__ out_tgt,
        const float* __restrict__ pos_align,
        const float* __restrict__ pos_ov,
        float* __restrict__ out_scores) {
    int i4 = blockIdx.x * blockDim.x + threadIdx.x;
    if (i4 >= BS * NA * (NC / 4)) return;
    int ba = i4 / (NC / 4);
    int c0 = (i4 - ba * (NC / 4)) * 4;
    float nm = 0.f; int lbl = -1;
    if (out_fg[ba] > 0.f) {
        int b   = ba / NA;
        int tgt = (int)out_tgt[ba];
        int bj  = b * NGT + tgt;
        nm  = al_res[ba] * pos_ov[bj] / (pos_align[bj] + EPSA);
        lbl = (int)out_labels[ba];
    }
    float4 v;
    v.x = (lbl == c0    ) ? nm : 0.f;
    v.y = (lbl == c0 + 1) ? nm : 0.f;
    v.z = (lbl == c0 + 2) ? nm : 0.f;
    v.w = (lbl == c0 + 3) ? nm : 0.f;
    ((float4*)out_scores)[i4] = v;
}

extern "C" void kernel_launch(void* const* d_in, const int* in_sizes, int n_in,
                              void* d_out, int out_size, void* d_ws, size_t ws_size,
                              hipStream_t stream) {
    const float* pd_scores = (const float*)d_in[0];
    const float* pd_bboxes = (const float*)d_in[1];
    const float* anc       = (const float*)d_in[2];
    const int*   gt_labels = (const int*)d_in[3];
    const float* gt_bboxes = (const float*)d_in[4];
    const float* mask_gt   = (const float*)d_in[5];

    // ---- workspace carve: [zeroed region | cand | al_res | amax] ----
    char* p = (char*)d_ws;
    u64*      bits        = (u64*)p;      p += (size_t)BS * NA * sizeof(u64);
    int*      cnt         = (int*)p;      p += (size_t)BS * NGT * sizeof(int);
    unsigned* pos_align_u = (unsigned*)p; p += (size_t)BS * NGT * sizeof(unsigned);
    unsigned* pos_ov_u    = (unsigned*)p; p += (size_t)BS * NGT * sizeof(unsigned);
    size_t zbytes = (size_t)(p - (char*)d_ws);
    u64*   cand   = (u64*)p;   p += (size_t)BS * NGT * CAP * sizeof(u64);
    float* al_res = (float*)p; p += (size_t)BS * NA * sizeof(float);
    unsigned char* amax_idx = (unsigned char*)p; p += (size_t)BS * NA;

    // ---- output carve (all float32, concatenated in return order) ----
    float* out_labels = (float*)d_out;                       // BS*NA
    float* out_bboxes = out_labels + (size_t)BS * NA;        // BS*NA*4
    float* out_scores = out_bboxes + (size_t)BS * NA * 4;    // BS*NA*NC
    float* out_fg     = out_scores + (size_t)BS * NA * NC;   // BS*NA
    float* out_tgt    = out_fg     + (size_t)BS * NA;        // BS*NA

    hipMemsetAsync(d_ws, 0, zbytes, stream);

    k1_pairs<<<BS * NCHUNK, 256, 0, stream>>>(pd_scores, pd_bboxes, anc, gt_labels,
                                              gt_bboxes, mask_gt, cand, cnt, amax_idx);
    k2_topk<<<BS * NGT / 4, 256, 0, stream>>>(cand, cnt, bits);
    k3_resolve<<<BS * NCHUNK, 256, 0, stream>>>(pd_scores, pd_bboxes, anc, gt_labels,
                                                gt_bboxes, mask_gt, bits, amax_idx,
                                                out_labels, out_bboxes, out_fg, out_tgt,
                                                al_res, pos_align_u, pos_ov_u);
    k5_scores<<<(BS * NA * (NC / 4) + 255) / 256, 256, 0, stream>>>(
        al_res, out_labels, out_fg, out_tgt,
        (const float*)pos_align_u, (const float*)pos_ov_u, out_scores);
}

// Round 5
// 72.353 us; speedup vs baseline: 8.6377x; 1.2356x over previous
//
#include <hip/hip_runtime.h>
#include <math.h>

#define BS   16
#define NA   8400
#define NGT  64
#define NC   80
#define TK   13
#define CAP  1024               // per-(b,j) candidate list capacity (worst case ~352)
#define WPB  512                // waves per batch image in k1
#define AW   ((NA + WPB - 1) / WPB)   // anchors per wave = 17
#define NCHUNK ((NA + 255) / 256)     // 33 (k3 blocks per batch)
#define EPSA 1e-9f
#define EPSC 1e-7f

typedef unsigned long long u64;

__device__ __forceinline__ u64 umax64(u64 a, u64 b) { return a > b ? a : b; }
__device__ __forceinline__ u64 umin64(u64 a, u64 b) { return a < b ? a : b; }

__device__ __forceinline__ u64 shfl_xor_u64(u64 v, int m) {
    int lo = __shfl_xor((int)(unsigned)v, m, 64);
    int hi = __shfl_xor((int)(unsigned)(v >> 32), m, 64);
    return ((u64)(unsigned)hi << 32) | (unsigned)lo;
}

// Merge two desc-sorted 16-lists, keep top-16 desc in t. Exact (bitonic).
__device__ __forceinline__ void merge16(u64* t, const u64* o) {
    u64 c[16];
#pragma unroll
    for (int i = 0; i < 16; ++i) c[i] = umax64(t[i], o[15 - i]);
#pragma unroll
    for (int d = 8; d >= 1; d >>= 1) {
#pragma unroll
        for (int i = 0; i < 16; ++i) {
            if ((i & d) == 0) {
                u64 hi = umax64(c[i], c[i + d]);
                u64 lo = umin64(c[i], c[i + d]);
                c[i] = hi; c[i + d] = lo;
            }
        }
    }
#pragma unroll
    for (int i = 0; i < 16; ++i) t[i] = c[i];
}

__device__ __forceinline__ void insert13(u64* t, u64 key) {
    u64 cur = key;
#pragma unroll
    for (int s = 0; s < 13; ++s) {
        u64 hi = umax64(t[s], cur);
        cur    = umin64(t[s], cur);
        t[s]   = hi;
    }
}

// identical expression in K1 and K3 -> bit-identical recompute
__device__ __forceinline__ float ciou_clip(float4 g, float4 p, float at1, float a1) {
    float w2 = p.z - p.x;
    float h2 = p.w - p.y + EPSC;
    float iw = fminf(g.z, p.z) - fmaxf(g.x, p.x);
    float ih = fminf(g.w, p.w) - fmaxf(g.y, p.y);
    float inter = fmaxf(iw, 0.f) * fmaxf(ih, 0.f);
    float uni   = a1 + w2 * h2 - inter + EPSC;
    float iou   = inter / uni;
    float cw = fmaxf(g.z, p.z) - fminf(g.x, p.x);
    float ch = fmaxf(g.w, p.w) - fminf(g.y, p.y);
    float c2 = cw * cw + ch * ch + EPSC;
    float dx = p.x + p.z - g.x - g.z;
    float dy = p.y + p.w - g.y - g.w;
    float rho2 = (dx * dx + dy * dy) * 0.25f;
    float dat  = atanf(w2 / h2) - at1;
    float v    = (4.0f / (float)(M_PI * M_PI)) * dat * dat;
    float alpha = v / (v - iou + (1.0f + EPSC));
    float ciou  = iou - (rho2 / c2 + v * alpha);
    return fmaxf(ciou, 0.f);
}

// ---------------- K1: lane-per-gt pair scan ----------------
// wave = (b, anchor chunk); lane = gt index j. gt data lives in registers.
// Per anchor: broadcast ap/p, 64 pair tests in parallel, CIoU on active lanes,
// candidate push per active lane, overlaps-argmax via ballot (+rare butterfly).
__global__ __launch_bounds__(256) void k1_pairs(
        const float* __restrict__ pd_scores,
        const float* __restrict__ pd_bboxes,
        const float* __restrict__ anc,
        const int*   __restrict__ gt_labels,
        const float* __restrict__ gt_bboxes,
        const float* __restrict__ mask_gt,
        u64* __restrict__ cand,
        int* __restrict__ cnt,
        unsigned char* __restrict__ amax_idx) {
    int wg   = blockIdx.x * 4 + (threadIdx.x >> 6);  // global wave id
    int b    = wg / WPB;
    int w    = wg - b * WPB;
    int lane = threadIdx.x & 63;
    int bj   = b * NGT + lane;

    float4 g   = ((const float4*)gt_bboxes)[bj];
    float  mgt = mask_gt[bj];
    int    lbl = gt_labels[bj];
    float w1 = g.z - g.x, h1 = g.w - g.y + EPSC;
    float at1 = atanf(w1 / h1);
    float a1  = w1 * h1;
    bool act  = mgt > 0.f;

    const float4* pbb = ((const float4*)pd_bboxes) + (size_t)b * NA;
    const float*  psc = pd_scores + (size_t)b * NA * NC;

    int a0   = w * AW;
    int aend = a0 + AW; if (aend > NA) aend = NA;

    for (int a = a0; a < aend; ++a) {
        float2 ap = ((const float2*)anc)[a];   // broadcast (same addr all lanes)
        float4 p  = pbb[a];                    // broadcast
        float dmin = fminf(fminf(ap.x - g.x, ap.y - g.y),
                           fminf(g.z - ap.x, g.w - ap.y));
        bool inside = dmin > EPSA;
        float o = 0.f;
        if (act && inside) {
            o = ciou_clip(g, p, at1, a1);
            float sc = psc[(size_t)a * NC + lbl];
            float o2 = o * o;
            float al = sc * (o2 * o2 * o2);          // score^1 * ovl^6
            u64 key = ((u64)__float_as_uint(al) << 32) |
                      (u64)(((unsigned)(16384 - a) << 1) | 1u);
            int pos = atomicAdd(&cnt[bj], 1);
            if (pos < CAP) cand[(size_t)bj * CAP + pos] = key;
        } else if (act && a < 16) {
            // zero filler: the 16 smallest-index entries dominate every outside
            // a>=16 zero key -> candidate set provably contains exact top-13
            u64 key = (u64)((unsigned)(16384 - a) << 1);
            int pos = atomicAdd(&cnt[bj], 1);
            if (pos < CAP) cand[(size_t)bj * CAP + pos] = key;
        }

        // overlaps-argmax over j (first max wins), lane-parallel
        u64 pb = __ballot(o > 0.f);
        int idx;
        if (__popcll(pb) <= 1) {
            idx = pb ? (__ffsll(pb) - 1) : 0;
        } else {
            u64 k = ((u64)__float_as_uint(o) << 6) | (unsigned)(63 - lane);
#pragma unroll
            for (int d = 1; d < 64; d <<= 1) k = umax64(k, shfl_xor_u64(k, d));
            idx = 63 - (int)(k & 63ULL);
        }
        if (lane == 0) amax_idx[(size_t)b * NA + a] = (unsigned char)idx;
    }
}

// ---------------- K2: wave-per-row top-13 merge ----------------
__global__ __launch_bounds__(256) void k2_topk(
        const u64* __restrict__ cand,
        const int* __restrict__ cnt,
        u64* __restrict__ bits) {
    int bj   = blockIdx.x * 4 + (threadIdx.x >> 6);
    int lane = threadIdx.x & 63;
    int b = bj >> 6, j = bj & 63;
    int n = cnt[bj]; if (n > CAP) n = CAP;
    const u64* lst = cand + (size_t)bj * CAP;

    u64 t[16];
#pragma unroll
    for (int i = 0; i < 16; ++i) t[i] = 0;
    for (int i = lane; i < n; i += 64) insert13(t, lst[i]);

#pragma unroll
    for (int d = 1; d < 64; d <<= 1) {
        u64 o16[16];
#pragma unroll
        for (int i = 0; i < 16; ++i) o16[i] = shfl_xor_u64(t[i], d);
        merge16(t, o16);
    }
    if (lane == 0) {
        u64 mybit = 1ULL << j;
#pragma unroll
        for (int it = 0; it < TK; ++it) {
            unsigned low = (unsigned)t[it];
            int a = 16384 - (int)(low >> 1);
            if (low & 1u)
                atomicOr(&bits[(size_t)b * NA + a], mybit);
        }
    }
}

// ---------------- K3: per-anchor resolve + pos-maxes + outputs ----------------
__global__ __launch_bounds__(256) void k3_resolve(
        const float* __restrict__ pd_scores,
        const float* __restrict__ pd_bboxes,
        const float* __restrict__ anc,
        const int*   __restrict__ gt_labels,
        const float* __restrict__ gt_bboxes,
        const float* __restrict__ mask_gt,
        const u64* __restrict__ bits,
        const unsigned char* __restrict__ amax_idx,
        float* __restrict__ out_labels,
        float* __restrict__ out_bboxes,
        float* __restrict__ out_fg,
        float* __restrict__ out_tgt,
        float* __restrict__ al_res,
        unsigned* __restrict__ pos_align_u,
        unsigned* __restrict__ pos_ov_u) {
    int bx = blockIdx.x;
    int b  = bx / NCHUNK;
    int a  = (bx % NCHUNK) * 256 + threadIdx.x;

    __shared__ float4 sg[NGT];
    __shared__ float  sat1[NGT], sa1[NGT], smgt[NGT];
    __shared__ int    slbl[NGT];
    if (threadIdx.x < NGT) {
        int j = threadIdx.x, bj = b * NGT + j;
        float4 g = ((const float4*)gt_bboxes)[bj];
        sg[j] = g;
        float w1 = g.z - g.x, h1 = g.w - g.y + EPSC;
        sat1[j] = atanf(w1 / h1);
        sa1[j]  = w1 * h1;
        smgt[j] = mask_gt[bj];
        slbl[j] = gt_labels[bj];
    }
    __syncthreads();
    if (a >= NA) return;

    size_t i = (size_t)b * NA + a;
    u64 mb = bits[i];
    int fg = __popcll(mb);
    int tgt;
    if (fg > 1)       tgt = amax_idx[i];                       // is_max override
    else if (fg == 1) tgt = __ffsll(mb) - 1;
    else              tgt = 0;

    float al = 0.f;
    if (fg > 0) {
        float4 g = sg[tgt];
        float2 ap = ((const float2*)anc)[a];
        float dmin = fminf(fminf(ap.x - g.x, ap.y - g.y),
                           fminf(g.z - ap.x, g.w - ap.y));
        if (smgt[tgt] > 0.f && dmin > EPSA) {
            float4 p = ((const float4*)pd_bboxes)[(size_t)b * NA + a];
            float o  = ciou_clip(g, p, sat1[tgt], sa1[tgt]);
            float sc = pd_scores[(size_t)b * NA * NC + (size_t)a * NC + slbl[tgt]];
            float o2 = o * o;
            al = sc * (o2 * o2 * o2);
            atomicMax(&pos_ov_u[b * NGT + tgt], __float_as_uint(o));
        }
        atomicMax(&pos_align_u[b * NGT + tgt], __float_as_uint(al));
    }
    al_res[i] = al;

    int lbl = slbl[tgt]; if (lbl < 0) lbl = 0;
    out_labels[i] = (float)lbl;
    ((float4*)out_bboxes)[i] = sg[tgt];
    out_fg[i]  = (fg > 0) ? 1.f : 0.f;
    out_tgt[i] = (float)tgt;
}

// ---------------- K5: fused norm + one-hot scores (float4 writes) ------------
__global__ __launch_bounds__(256) void k5_scores(
        const float* __restrict__ al_res,
        const float* __restrict__ out_labels,
        const float* __restrict__ out_fg,
        const float* __restrict__ out_tgt,
        const float* __restrict__ pos_align,
        const float* __restrict__ pos_ov,
        float* __restrict__ out_scores) {
    int i4 = blockIdx.x * blockDim.x + threadIdx.x;
    if (i4 >= BS * NA * (NC / 4)) return;
    int ba = i4 / (NC / 4);
    int c0 = (i4 - ba * (NC / 4)) * 4;
    float nm = 0.f; int lbl = -1;
    if (out_fg[ba] > 0.f) {
        int b   = ba / NA;
        int tgt = (int)out_tgt[ba];
        int bj  = b * NGT + tgt;
        nm  = al_res[ba] * pos_ov[bj] / (pos_align[bj] + EPSA);
        lbl = (int)out_labels[ba];
    }
    float4 v;
    v.x = (lbl == c0    ) ? nm : 0.f;
    v.y = (lbl == c0 + 1) ? nm : 0.f;
    v.z = (lbl == c0 + 2) ? nm : 0.f;
    v.w = (lbl == c0 + 3) ? nm : 0.f;
    ((float4*)out_scores)[i4] = v;
}

extern "C" void kernel_launch(void* const* d_in, const int* in_sizes, int n_in,
                              void* d_out, int out_size, void* d_ws, size_t ws_size,
                              hipStream_t stream) {
    const float* pd_scores = (const float*)d_in[0];
    const float* pd_bboxes = (const float*)d_in[1];
    const float* anc       = (const float*)d_in[2];
    const int*   gt_labels = (const int*)d_in[3];
    const float* gt_bboxes = (const float*)d_in[4];
    const float* mask_gt   = (const float*)d_in[5];

    // ---- workspace carve: [zeroed region | cand | al_res | amax] ----
    char* p = (char*)d_ws;
    u64*      bits        = (u64*)p;      p += (size_t)BS * NA * sizeof(u64);
    int*      cnt         = (int*)p;      p += (size_t)BS * NGT * sizeof(int);
    unsigned* pos_align_u = (unsigned*)p; p += (size_t)BS * NGT * sizeof(unsigned);
    unsigned* pos_ov_u    = (unsigned*)p; p += (size_t)BS * NGT * sizeof(unsigned);
    size_t zbytes = (size_t)(p - (char*)d_ws);
    u64*   cand   = (u64*)p;   p += (size_t)BS * NGT * CAP * sizeof(u64);
    float* al_res = (float*)p; p += (size_t)BS * NA * sizeof(float);
    unsigned char* amax_idx = (unsigned char*)p; p += (size_t)BS * NA;

    // ---- output carve (all float32, concatenated in return order) ----
    float* out_labels = (float*)d_out;                       // BS*NA
    float* out_bboxes = out_labels + (size_t)BS * NA;        // BS*NA*4
    float* out_scores = out_bboxes + (size_t)BS * NA * 4;    // BS*NA*NC
    float* out_fg     = out_scores + (size_t)BS * NA * NC;   // BS*NA
    float* out_tgt    = out_fg     + (size_t)BS * NA;        // BS*NA

    hipMemsetAsync(d_ws, 0, zbytes, stream);

    k1_pairs<<<BS * WPB / 4, 256, 0, stream>>>(pd_scores, pd_bboxes, anc, gt_labels,
                                               gt_bboxes, mask_gt, cand, cnt, amax_idx);
    k2_topk<<<BS * NGT / 4, 256, 0, stream>>>(cand, cnt, bits);
    k3_resolve<<<BS * NCHUNK, 256, 0, stream>>>(pd_scores, pd_bboxes, anc, gt_labels,
                                                gt_bboxes, mask_gt, bits, amax_idx,
                                                out_labels, out_bboxes, out_fg, out_tgt,
                                                al_res, pos_align_u, pos_ov_u);
    k5_scores<<<(BS * NA * (NC / 4) + 255) / 256, 256, 0, stream>>>(
        al_res, out_labels, out_fg, out_tgt,
        (const float*)pos_align_u, (const float*)pos_ov_u, out_scores);
}

// Round 6
// 72.265 us; speedup vs baseline: 8.6482x; 1.0012x over previous
//
#include <hip/hip_runtime.h>
#include <math.h>

#define BS   16
#define NA   8400
#define NGT  64
#define NC   80
#define TK   13
#define CAP  1024               // per-(b,j) candidate list capacity (worst case ~352)
#define WPB  512                // waves per batch image in k1
#define AW   ((NA + WPB - 1) / WPB)   // anchors per wave = 17
#define NCHUNK ((NA + 255) / 256)     // 33 (k3 blocks per batch)
#define EPSA 1e-9f
#define EPSC 1e-7f

typedef unsigned long long u64;

__device__ __forceinline__ u64 umax64(u64 a, u64 b) { return a > b ? a : b; }
__device__ __forceinline__ u64 umin64(u64 a, u64 b) { return a < b ? a : b; }

__device__ __forceinline__ u64 shfl_xor_u64(u64 v, int m) {
    int lo = __shfl_xor((int)(unsigned)v, m, 64);
    int hi = __shfl_xor((int)(unsigned)(v >> 32), m, 64);
    return ((u64)(unsigned)hi << 32) | (unsigned)lo;
}

// Merge two desc-sorted 16-lists, keep top-16 desc in t. Exact (bitonic).
__device__ __forceinline__ void merge16(u64* t, const u64* o) {
    u64 c[16];
#pragma unroll
    for (int i = 0; i < 16; ++i) c[i] = umax64(t[i], o[15 - i]);
#pragma unroll
    for (int d = 8; d >= 1; d >>= 1) {
#pragma unroll
        for (int i = 0; i < 16; ++i) {
            if ((i & d) == 0) {
                u64 hi = umax64(c[i], c[i + d]);
                u64 lo = umin64(c[i], c[i + d]);
                c[i] = hi; c[i + d] = lo;
            }
        }
    }
#pragma unroll
    for (int i = 0; i < 16; ++i) t[i] = c[i];
}

__device__ __forceinline__ void insert13(u64* t, u64 key) {
    u64 cur = key;
#pragma unroll
    for (int s = 0; s < 13; ++s) {
        u64 hi = umax64(t[s], cur);
        cur    = umin64(t[s], cur);
        t[s]   = hi;
    }
}

// identical expression in K1 and K3 -> bit-identical recompute
__device__ __forceinline__ float ciou_clip(float4 g, float4 p, float at1, float a1) {
    float w2 = p.z - p.x;
    float h2 = p.w - p.y + EPSC;
    float iw = fminf(g.z, p.z) - fmaxf(g.x, p.x);
    float ih = fminf(g.w, p.w) - fmaxf(g.y, p.y);
    float inter = fmaxf(iw, 0.f) * fmaxf(ih, 0.f);
    float uni   = a1 + w2 * h2 - inter + EPSC;
    float iou   = inter / uni;
    float cw = fmaxf(g.z, p.z) - fminf(g.x, p.x);
    float ch = fmaxf(g.w, p.w) - fminf(g.y, p.y);
    float c2 = cw * cw + ch * ch + EPSC;
    float dx = p.x + p.z - g.x - g.z;
    float dy = p.y + p.w - g.y - g.w;
    float rho2 = (dx * dx + dy * dy) * 0.25f;
    float dat  = atanf(w2 / h2) - at1;
    float v    = (4.0f / (float)(M_PI * M_PI)) * dat * dat;
    float alpha = v / (v - iou + (1.0f + EPSC));
    float ciou  = iou - (rho2 / c2 + v * alpha);
    return fmaxf(ciou, 0.f);
}

// ---------------- K0: zero the atomic-target region (replaces slow runtime fill)
__global__ __launch_bounds__(256) void k0_init(uint4* __restrict__ p, int n16) {
    int i = blockIdx.x * 256 + threadIdx.x;
    if (i < n16) p[i] = make_uint4(0u, 0u, 0u, 0u);
}

// ---------------- K1: lane-per-gt pair scan ----------------
// wave = (b, anchor chunk); lane = gt index j. gt data lives in registers.
__global__ __launch_bounds__(256) void k1_pairs(
        const float* __restrict__ pd_scores,
        const float* __restrict__ pd_bboxes,
        const float* __restrict__ anc,
        const int*   __restrict__ gt_labels,
        const float* __restrict__ gt_bboxes,
        const float* __restrict__ mask_gt,
        u64* __restrict__ cand,
        int* __restrict__ cnt,
        unsigned char* __restrict__ amax_idx) {
    int wg   = blockIdx.x * 4 + (threadIdx.x >> 6);  // global wave id
    int b    = wg / WPB;
    int w    = wg - b * WPB;
    int lane = threadIdx.x & 63;
    int bj   = b * NGT + lane;

    float4 g   = ((const float4*)gt_bboxes)[bj];
    float  mgt = mask_gt[bj];
    int    lbl = gt_labels[bj];
    float w1 = g.z - g.x, h1 = g.w - g.y + EPSC;
    float at1 = atanf(w1 / h1);
    float a1  = w1 * h1;
    bool act  = mgt > 0.f;

    const float4* pbb = ((const float4*)pd_bboxes) + (size_t)b * NA;
    const float*  psc = pd_scores + (size_t)b * NA * NC;

    int a0   = w * AW;
    int aend = a0 + AW; if (aend > NA) aend = NA;

    for (int a = a0; a < aend; ++a) {
        float2 ap = ((const float2*)anc)[a];   // broadcast (same addr all lanes)
        float4 p  = pbb[a];                    // broadcast
        float dmin = fminf(fminf(ap.x - g.x, ap.y - g.y),
                           fminf(g.z - ap.x, g.w - ap.y));
        bool inside = dmin > EPSA;
        float o = 0.f;
        if (act && inside) {
            o = ciou_clip(g, p, at1, a1);
            float sc = psc[(size_t)a * NC + lbl];
            float o2 = o * o;
            float al = sc * (o2 * o2 * o2);          // score^1 * ovl^6
            u64 key = ((u64)__float_as_uint(al) << 32) |
                      (u64)(((unsigned)(16384 - a) << 1) | 1u);
            int pos = atomicAdd(&cnt[bj], 1);
            if (pos < CAP) cand[(size_t)bj * CAP + pos] = key;
        } else if (act && a < 16) {
            // zero filler: the 16 smallest-index entries dominate every outside
            // a>=16 zero key -> candidate set provably contains exact top-13
            u64 key = (u64)((unsigned)(16384 - a) << 1);
            int pos = atomicAdd(&cnt[bj], 1);
            if (pos < CAP) cand[(size_t)bj * CAP + pos] = key;
        }

        // overlaps-argmax over j (first max wins), lane-parallel
        u64 pb = __ballot(o > 0.f);
        int idx;
        if (__popcll(pb) <= 1) {
            idx = pb ? (__ffsll(pb) - 1) : 0;
        } else {
            u64 k = ((u64)__float_as_uint(o) << 6) | (unsigned)(63 - lane);
#pragma unroll
            for (int d = 1; d < 64; d <<= 1) k = umax64(k, shfl_xor_u64(k, d));
            idx = 63 - (int)(k & 63ULL);
        }
        if (lane == 0) amax_idx[(size_t)b * NA + a] = (unsigned char)idx;
    }
}

// ---------------- K2: wave-per-row top-13 merge ----------------
__global__ __launch_bounds__(256) void k2_topk(
        const u64* __restrict__ cand,
        const int* __restrict__ cnt,
        u64* __restrict__ bits) {
    int bj   = blockIdx.x * 4 + (threadIdx.x >> 6);
    int lane = threadIdx.x & 63;
    int b = bj >> 6, j = bj & 63;
    int n = cnt[bj]; if (n > CAP) n = CAP;
    const u64* lst = cand + (size_t)bj * CAP;

    u64 t[16];
#pragma unroll
    for (int i = 0; i < 16; ++i) t[i] = 0;
    for (int i = lane; i < n; i += 64) insert13(t, lst[i]);

#pragma unroll
    for (int d = 1; d < 64; d <<= 1) {
        u64 o16[16];
#pragma unroll
        for (int i = 0; i < 16; ++i) o16[i] = shfl_xor_u64(t[i], d);
        merge16(t, o16);
    }
    if (lane == 0) {
        u64 mybit = 1ULL << j;
#pragma unroll
        for (int it = 0; it < TK; ++it) {
            unsigned low = (unsigned)t[it];
            int a = 16384 - (int)(low >> 1);
            if (low & 1u)
                atomicOr(&bits[(size_t)b * NA + a], mybit);
        }
    }
}

// ---------------- K3: per-anchor resolve + pos-maxes + outputs ----------------
__global__ __launch_bounds__(256) void k3_resolve(
        const float* __restrict__ pd_scores,
        const float* __restrict__ pd_bboxes,
        const float* __restrict__ anc,
        const int*   __restrict__ gt_labels,
        const float* __restrict__ gt_bboxes,
        const float* __restrict__ mask_gt,
        const u64* __restrict__ bits,
        const unsigned char* __restrict__ amax_idx,
        float* __restrict__ out_labels,
        float* __restrict__ out_bboxes,
        float* __restrict__ out_fg,
        float* __restrict__ out_tgt,
        float* __restrict__ al_res,
        unsigned* __restrict__ pos_align_u,
        unsigned* __restrict__ pos_ov_u) {
    int bx = blockIdx.x;
    int b  = bx / NCHUNK;
    int a  = (bx % NCHUNK) * 256 + threadIdx.x;

    __shared__ float4 sg[NGT];
    __shared__ float  sat1[NGT], sa1[NGT], smgt[NGT];
    __shared__ int    slbl[NGT];
    if (threadIdx.x < NGT) {
        int j = threadIdx.x, bj = b * NGT + j;
        float4 g = ((const float4*)gt_bboxes)[bj];
        sg[j] = g;
        float w1 = g.z - g.x, h1 = g.w - g.y + EPSC;
        sat1[j] = atanf(w1 / h1);
        sa1[j]  = w1 * h1;
        smgt[j] = mask_gt[bj];
        slbl[j] = gt_labels[bj];
    }
    __syncthreads();
    if (a >= NA) return;

    size_t i = (size_t)b * NA + a;
    u64 mb = bits[i];
    int fg = __popcll(mb);
    int tgt;
    if (fg > 1)       tgt = amax_idx[i];                       // is_max override
    else if (fg == 1) tgt = __ffsll(mb) - 1;
    else              tgt = 0;

    float al = 0.f;
    if (fg > 0) {
        float4 g = sg[tgt];
        float2 ap = ((const float2*)anc)[a];
        float dmin = fminf(fminf(ap.x - g.x, ap.y - g.y),
                           fminf(g.z - ap.x, g.w - ap.y));
        if (smgt[tgt] > 0.f && dmin > EPSA) {
            float4 p = ((const float4*)pd_bboxes)[(size_t)b * NA + a];
            float o  = ciou_clip(g, p, sat1[tgt], sa1[tgt]);
            float sc = pd_scores[(size_t)b * NA * NC + (size_t)a * NC + slbl[tgt]];
            float o2 = o * o;
            al = sc * (o2 * o2 * o2);
            atomicMax(&pos_ov_u[b * NGT + tgt], __float_as_uint(o));
        }
        atomicMax(&pos_align_u[b * NGT + tgt], __float_as_uint(al));
    }
    al_res[i] = al;

    int lbl = slbl[tgt]; if (lbl < 0) lbl = 0;
    out_labels[i] = (float)lbl;
    ((float4*)out_bboxes)[i] = sg[tgt];
    out_fg[i]  = (fg > 0) ? 1.f : 0.f;
    out_tgt[i] = (float)tgt;
}

// ---------------- K5: fused norm + one-hot scores (float4 writes) ------------
__global__ __launch_bounds__(256) void k5_scores(
        const float* __restrict__ al_res,
        const float* __restrict__ out_labels,
        const float* __restrict__ out_fg,
        const float* __restrict__ out_tgt,
        const float* __restrict__ pos_align,
        const float* __restrict__ pos_ov,
        float* __restrict__ out_scores) {
    int i4 = blockIdx.x * blockDim.x + threadIdx.x;
    if (i4 >= BS * NA * (NC / 4)) return;
    int ba = i4 / (NC / 4);
    int c0 = (i4 - ba * (NC / 4)) * 4;
    float nm = 0.f; int lbl = -1;
    if (out_fg[ba] > 0.f) {
        int b   = ba / NA;
        int tgt = (int)out_tgt[ba];
        int bj  = b * NGT + tgt;
        nm  = al_res[ba] * pos_ov[bj] / (pos_align[bj] + EPSA);
        lbl = (int)out_labels[ba];
    }
    float4 v;
    v.x = (lbl == c0    ) ? nm : 0.f;
    v.y = (lbl == c0 + 1) ? nm : 0.f;
    v.z = (lbl == c0 + 2) ? nm : 0.f;
    v.w = (lbl == c0 + 3) ? nm : 0.f;
    ((float4*)out_scores)[i4] = v;
}

extern "C" void kernel_launch(void* const* d_in, const int* in_sizes, int n_in,
                              void* d_out, int out_size, void* d_ws, size_t ws_size,
                              hipStream_t stream) {
    const float* pd_scores = (const float*)d_in[0];
    const float* pd_bboxes = (const float*)d_in[1];
    const float* anc       = (const float*)d_in[2];
    const int*   gt_labels = (const int*)d_in[3];
    const float* gt_bboxes = (const float*)d_in[4];
    const float* mask_gt   = (const float*)d_in[5];

    // ---- workspace carve: [zeroed region | cand | al_res | amax] ----
    char* p = (char*)d_ws;
    u64*      bits        = (u64*)p;      p += (size_t)BS * NA * sizeof(u64);
    int*      cnt         = (int*)p;      p += (size_t)BS * NGT * sizeof(int);
    unsigned* pos_align_u = (unsigned*)p; p += (size_t)BS * NGT * sizeof(unsigned);
    unsigned* pos_ov_u    = (unsigned*)p; p += (size_t)BS * NGT * sizeof(unsigned);
    size_t zbytes = (size_t)(p - (char*)d_ws);
    u64*   cand   = (u64*)p;   p += (size_t)BS * NGT * CAP * sizeof(u64);
    float* al_res = (float*)p; p += (size_t)BS * NA * sizeof(float);
    unsigned char* amax_idx = (unsigned char*)p; p += (size_t)BS * NA;

    // ---- output carve (all float32, concatenated in return order) ----
    float* out_labels = (float*)d_out;                       // BS*NA
    float* out_bboxes = out_labels + (size_t)BS * NA;        // BS*NA*4
    float* out_scores = out_bboxes + (size_t)BS * NA * 4;    // BS*NA*NC
    float* out_fg     = out_scores + (size_t)BS * NA * NC;   // BS*NA
    float* out_tgt    = out_fg     + (size_t)BS * NA;        // BS*NA

    int n16 = (int)(zbytes / 16);   // zbytes = 1,087,488 -> divisible by 16
    k0_init<<<(n16 + 255) / 256, 256, 0, stream>>>((uint4*)d_ws, n16);

    k1_pairs<<<BS * WPB / 4, 256, 0, stream>>>(pd_scores, pd_bboxes, anc, gt_labels,
                                               gt_bboxes, mask_gt, cand, cnt, amax_idx);
    k2_topk<<<BS * NGT / 4, 256, 0, stream>>>(cand, cnt, bits);
    k3_resolve<<<BS * NCHUNK, 256, 0, stream>>>(pd_scores, pd_bboxes, anc, gt_labels,
                                                gt_bboxes, mask_gt, bits, amax_idx,
                                                out_labels, out_bboxes, out_fg, out_tgt,
                                                al_res, pos_align_u, pos_ov_u);
    k5_scores<<<(BS * NA * (NC / 4) + 255) / 256, 256, 0, stream>>>(
        al_res, out_labels, out_fg, out_tgt,
        (const float*)pos_align_u, (const float*)pos_ov_u, out_scores);
}

// Round 8
// 71.758 us; speedup vs baseline: 8.7093x; 1.0071x over previous
//
#include <hip/hip_runtime.h>
#include <math.h>

#define BS   16
#define NA   8400
#define NGT  64
#define NC   80
#define TK   13
#define CAP  1024               // per-(b,j) candidate list capacity (worst case ~352)
#define WPB  512                // waves per batch image in k1
#define AW   ((NA + WPB - 1) / WPB)   // anchors per wave = 17
#define NCHUNK ((NA + 255) / 256)     // 33 (k3 blocks per batch)
#define EPSA 1e-9f
#define EPSC 1e-7f

typedef unsigned long long u64;
typedef float f32x4 __attribute__((ext_vector_type(4)));   // native vec for nt-store

__device__ __forceinline__ u64 umax64(u64 a, u64 b) { return a > b ? a : b; }
__device__ __forceinline__ u64 umin64(u64 a, u64 b) { return a < b ? a : b; }

__device__ __forceinline__ u64 shfl_xor_u64(u64 v, int m) {
    int lo = __shfl_xor((int)(unsigned)v, m, 64);
    int hi = __shfl_xor((int)(unsigned)(v >> 32), m, 64);
    return ((u64)(unsigned)hi << 32) | (unsigned)lo;
}

// Merge two desc-sorted 16-lists, keep top-16 desc in t. Exact (bitonic).
__device__ __forceinline__ void merge16(u64* t, const u64* o) {
    u64 c[16];
#pragma unroll
    for (int i = 0; i < 16; ++i) c[i] = umax64(t[i], o[15 - i]);
#pragma unroll
    for (int d = 8; d >= 1; d >>= 1) {
#pragma unroll
        for (int i = 0; i < 16; ++i) {
            if ((i & d) == 0) {
                u64 hi = umax64(c[i], c[i + d]);
                u64 lo = umin64(c[i], c[i + d]);
                c[i] = hi; c[i + d] = lo;
            }
        }
    }
#pragma unroll
    for (int i = 0; i < 16; ++i) t[i] = c[i];
}

__device__ __forceinline__ void insert13(u64* t, u64 key) {
    u64 cur = key;
#pragma unroll
    for (int s = 0; s < 13; ++s) {
        u64 hi = umax64(t[s], cur);
        cur    = umin64(t[s], cur);
        t[s]   = hi;
    }
}

// identical expression in K1 and K3 -> bit-identical recompute
__device__ __forceinline__ float ciou_clip(float4 g, float4 p, float at1, float a1) {
    float w2 = p.z - p.x;
    float h2 = p.w - p.y + EPSC;
    float iw = fminf(g.z, p.z) - fmaxf(g.x, p.x);
    float ih = fminf(g.w, p.w) - fmaxf(g.y, p.y);
    float inter = fmaxf(iw, 0.f) * fmaxf(ih, 0.f);
    float uni   = a1 + w2 * h2 - inter + EPSC;
    float iou   = inter / uni;
    float cw = fmaxf(g.z, p.z) - fminf(g.x, p.x);
    float ch = fmaxf(g.w, p.w) - fminf(g.y, p.y);
    float c2 = cw * cw + ch * ch + EPSC;
    float dx = p.x + p.z - g.x - g.z;
    float dy = p.y + p.w - g.y - g.w;
    float rho2 = (dx * dx + dy * dy) * 0.25f;
    float dat  = atanf(w2 / h2) - at1;
    float v    = (4.0f / (float)(M_PI * M_PI)) * dat * dat;
    float alpha = v / (v - iou + (1.0f + EPSC));
    float ciou  = iou - (rho2 / c2 + v * alpha);
    return fmaxf(ciou, 0.f);
}

// ---------------- K0: zero the atomic-target region ----------------
__global__ __launch_bounds__(256) void k0_init(uint4* __restrict__ p, int n16) {
    int i = blockIdx.x * 256 + threadIdx.x;
    if (i < n16) p[i] = make_uint4(0u, 0u, 0u, 0u);
}

// ---------------- K1: lane-per-gt pair scan (software-pipelined) ----------
// wave = (b, anchor chunk); lane = gt index j. gt data lives in registers.
__global__ __launch_bounds__(256) void k1_pairs(
        const float* __restrict__ pd_scores,
        const float* __restrict__ pd_bboxes,
        const float* __restrict__ anc,
        const int*   __restrict__ gt_labels,
        const float* __restrict__ gt_bboxes,
        const float* __restrict__ mask_gt,
        u64* __restrict__ cand,
        int* __restrict__ cnt,
        unsigned char* __restrict__ amax_idx) {
    int wg   = blockIdx.x * 4 + (threadIdx.x >> 6);  // global wave id
    int b    = wg / WPB;
    int w    = wg - b * WPB;
    int lane = threadIdx.x & 63;
    int bj   = b * NGT + lane;

    float4 g   = ((const float4*)gt_bboxes)[bj];
    float  mgt = mask_gt[bj];
    int    lbl = gt_labels[bj];
    float w1 = g.z - g.x, h1 = g.w - g.y + EPSC;
    float at1 = atanf(w1 / h1);
    float a1  = w1 * h1;
    bool act  = mgt > 0.f;

    const float4* pbb = ((const float4*)pd_bboxes) + (size_t)b * NA;
    const float*  psc = pd_scores + (size_t)b * NA * NC;

    int a0   = w * AW;
    int aend = a0 + AW; if (aend > NA) aend = NA;
    if (a0 >= aend) return;

    float2 ap = ((const float2*)anc)[a0];   // broadcast
    float4 p  = pbb[a0];

    for (int a = a0; a < aend; ++a) {
        // prefetch next iteration (hides broadcast-load latency under compute)
        float2 apn = ap; float4 pn = p;
        if (a + 1 < aend) {
            apn = ((const float2*)anc)[a + 1];
            pn  = pbb[a + 1];
        }

        float dmin = fminf(fminf(ap.x - g.x, ap.y - g.y),
                           fminf(g.z - ap.x, g.w - ap.y));
        bool inside = dmin > EPSA;
        float o = 0.f;
        if (act && inside) {
            o = ciou_clip(g, p, at1, a1);
            float sc = psc[(size_t)a * NC + lbl];
            float o2 = o * o;
            float al = sc * (o2 * o2 * o2);          // score^1 * ovl^6
            u64 key = ((u64)__float_as_uint(al) << 32) |
                      (u64)(((unsigned)(16384 - a) << 1) | 1u);
            int pos = atomicAdd(&cnt[bj], 1);
            if (pos < CAP) cand[(size_t)bj * CAP + pos] = key;
        } else if (act && a < 16) {
            // zero filler: the 16 smallest-index entries dominate every outside
            // a>=16 zero key -> candidate set provably contains exact top-13
            u64 key = (u64)((unsigned)(16384 - a) << 1);
            int pos = atomicAdd(&cnt[bj], 1);
            if (pos < CAP) cand[(size_t)bj * CAP + pos] = key;
        }

        // overlaps-argmax over j (first max wins), lane-parallel
        u64 pb = __ballot(o > 0.f);
        int idx;
        if (__popcll(pb) <= 1) {
            idx = pb ? (__ffsll(pb) - 1) : 0;
        } else {
            u64 k = ((u64)__float_as_uint(o) << 6) | (unsigned)(63 - lane);
#pragma unroll
            for (int d = 1; d < 64; d <<= 1) k = umax64(k, shfl_xor_u64(k, d));
            idx = 63 - (int)(k & 63ULL);
        }
        if (lane == 0) amax_idx[(size_t)b * NA + a] = (unsigned char)idx;

        ap = apn; p = pn;
    }
}

// ---------------- K2: wave-per-row top-13 merge ----------------
__global__ __launch_bounds__(256) void k2_topk(
        const u64* __restrict__ cand,
        const int* __restrict__ cnt,
        u64* __restrict__ bits) {
    int bj   = blockIdx.x * 4 + (threadIdx.x >> 6);
    int lane = threadIdx.x & 63;
    int b = bj >> 6, j = bj & 63;
    int n = cnt[bj]; if (n > CAP) n = CAP;
    const u64* lst = cand + (size_t)bj * CAP;

    u64 t[16];
#pragma unroll
    for (int i = 0; i < 16; ++i) t[i] = 0;
    for (int i = lane; i < n; i += 64) insert13(t, lst[i]);

#pragma unroll
    for (int d = 1; d < 64; d <<= 1) {
        u64 o16[16];
#pragma unroll
        for (int i = 0; i < 16; ++i) o16[i] = shfl_xor_u64(t[i], d);
        merge16(t, o16);
    }
    if (lane == 0) {
        u64 mybit = 1ULL << j;
#pragma unroll
        for (int it = 0; it < TK; ++it) {
            unsigned low = (unsigned)t[it];
            int a = 16384 - (int)(low >> 1);
            if (low & 1u)
                atomicOr(&bits[(size_t)b * NA + a], mybit);
        }
    }
}

// ---------------- K3: per-anchor resolve + pos-maxes + outputs ----------------
__global__ __launch_bounds__(256) void k3_resolve(
        const float* __restrict__ pd_scores,
        const float* __restrict__ pd_bboxes,
        const float* __restrict__ anc,
        const int*   __restrict__ gt_labels,
        const float* __restrict__ gt_bboxes,
        const float* __restrict__ mask_gt,
        const u64* __restrict__ bits,
        const unsigned char* __restrict__ amax_idx,
        float* __restrict__ out_labels,
        float* __restrict__ out_bboxes,
        float* __restrict__ out_fg,
        float* __restrict__ out_tgt,
        float* __restrict__ al_res,
        unsigned* __restrict__ pos_align_u,
        unsigned* __restrict__ pos_ov_u) {
    int bx = blockIdx.x;
    int b  = bx / NCHUNK;
    int a  = (bx % NCHUNK) * 256 + threadIdx.x;

    __shared__ float4 sg[NGT];
    __shared__ float  sat1[NGT], sa1[NGT], smgt[NGT];
    __shared__ int    slbl[NGT];
    if (threadIdx.x < NGT) {
        int j = threadIdx.x, bj = b * NGT + j;
        float4 g = ((const float4*)gt_bboxes)[bj];
        sg[j] = g;
        float w1 = g.z - g.x, h1 = g.w - g.y + EPSC;
        sat1[j] = atanf(w1 / h1);
        sa1[j]  = w1 * h1;
        smgt[j] = mask_gt[bj];
        slbl[j] = gt_labels[bj];
    }
    __syncthreads();
    if (a >= NA) return;

    size_t i = (size_t)b * NA + a;
    u64 mb = bits[i];
    int fg = __popcll(mb);
    int tgt;
    if (fg > 1)       tgt = amax_idx[i];                       // is_max override
    else if (fg == 1) tgt = __ffsll(mb) - 1;
    else              tgt = 0;

    float al = 0.f;
    if (fg > 0) {
        float4 g = sg[tgt];
        float2 ap = ((const float2*)anc)[a];
        float dmin = fminf(fminf(ap.x - g.x, ap.y - g.y),
                           fminf(g.z - ap.x, g.w - ap.y));
        if (smgt[tgt] > 0.f && dmin > EPSA) {
            float4 p = ((const float4*)pd_bboxes)[(size_t)b * NA + a];
            float o  = ciou_clip(g, p, sat1[tgt], sa1[tgt]);
            float sc = pd_scores[(size_t)b * NA * NC + (size_t)a * NC + slbl[tgt]];
            float o2 = o * o;
            al = sc * (o2 * o2 * o2);
            atomicMax(&pos_ov_u[b * NGT + tgt], __float_as_uint(o));
        }
        atomicMax(&pos_align_u[b * NGT + tgt], __float_as_uint(al));
    }
    al_res[i] = al;

    int lbl = slbl[tgt]; if (lbl < 0) lbl = 0;
    out_labels[i] = (float)lbl;
    float4 gb = sg[tgt];
    f32x4 gbv; gbv.x = gb.x; gbv.y = gb.y; gbv.z = gb.z; gbv.w = gb.w;
    __builtin_nontemporal_store(gbv, &((f32x4*)out_bboxes)[i]);
    out_fg[i]  = (fg > 0) ? 1.f : 0.f;
    out_tgt[i] = (float)tgt;
}

// ---------------- K5: fused norm + one-hot scores (nt float4 writes) ---------
__global__ __launch_bounds__(256) void k5_scores(
        const float* __restrict__ al_res,
        const float* __restrict__ out_labels,
        const float* __restrict__ out_fg,
        const float* __restrict__ out_tgt,
        const float* __restrict__ pos_align,
        const float* __restrict__ pos_ov,
        float* __restrict__ out_scores) {
    int i4 = blockIdx.x * blockDim.x + threadIdx.x;
    if (i4 >= BS * NA * (NC / 4)) return;
    int ba = i4 / (NC / 4);
    int c0 = (i4 - ba * (NC / 4)) * 4;
    float nm = 0.f; int lbl = -1;
    if (out_fg[ba] > 0.f) {
        int b   = ba / NA;
        int tgt = (int)out_tgt[ba];
        int bj  = b * NGT + tgt;
        nm  = al_res[ba] * pos_ov[bj] / (pos_align[bj] + EPSA);
        lbl = (int)out_labels[ba];
    }
    f32x4 v;
    v.x = (lbl == c0    ) ? nm : 0.f;
    v.y = (lbl == c0 + 1) ? nm : 0.f;
    v.z = (lbl == c0 + 2) ? nm : 0.f;
    v.w = (lbl == c0 + 3) ? nm : 0.f;
    __builtin_nontemporal_store(v, &((f32x4*)out_scores)[i4]);
}

extern "C" void kernel_launch(void* const* d_in, const int* in_sizes, int n_in,
                              void* d_out, int out_size, void* d_ws, size_t ws_size,
                              hipStream_t stream) {
    const float* pd_scores = (const float*)d_in[0];
    const float* pd_bboxes = (const float*)d_in[1];
    const float* anc       = (const float*)d_in[2];
    const int*   gt_labels = (const int*)d_in[3];
    const float* gt_bboxes = (const float*)d_in[4];
    const float* mask_gt   = (const float*)d_in[5];

    // ---- workspace carve: [zeroed region | cand | al_res | amax] ----
    char* p = (char*)d_ws;
    u64*      bits        = (u64*)p;      p += (size_t)BS * NA * sizeof(u64);
    int*      cnt         = (int*)p;      p += (size_t)BS * NGT * sizeof(int);
    unsigned* pos_align_u = (unsigned*)p; p += (size_t)BS * NGT * sizeof(unsigned);
    unsigned* pos_ov_u    = (unsigned*)p; p += (size_t)BS * NGT * sizeof(unsigned);
    size_t zbytes = (size_t)(p - (char*)d_ws);
    u64*   cand   = (u64*)p;   p += (size_t)BS * NGT * CAP * sizeof(u64);
    float* al_res = (float*)p; p += (size_t)BS * NA * sizeof(float);
    unsigned char* amax_idx = (unsigned char*)p; p += (size_t)BS * NA;

    // ---- output carve (all float32, concatenated in return order) ----
    float* out_labels = (float*)d_out;                       // BS*NA
    float* out_bboxes = out_labels + (size_t)BS * NA;        // BS*NA*4
    float* out_scores = out_bboxes + (size_t)BS * NA * 4;    // BS*NA*NC
    float* out_fg     = out_scores + (size_t)BS * NA * NC;   // BS*NA
    float* out_tgt    = out_fg     + (size_t)BS * NA;        // BS*NA

    int n16 = (int)(zbytes / 16);   // zbytes divisible by 16
    k0_init<<<(n16 + 255) / 256, 256, 0, stream>>>((uint4*)d_ws, n16);

    k1_pairs<<<BS * WPB / 4, 256, 0, stream>>>(pd_scores, pd_bboxes, anc, gt_labels,
                                               gt_bboxes, mask_gt, cand, cnt, amax_idx);
    k2_topk<<<BS * NGT / 4, 256, 0, stream>>>(cand, cnt, bits);
    k3_resolve<<<BS * NCHUNK, 256, 0, stream>>>(pd_scores, pd_bboxes, anc, gt_labels,
                                                gt_bboxes, mask_gt, bits, amax_idx,
                                                out_labels, out_bboxes, out_fg, out_tgt,
                                                al_res, pos_align_u, pos_ov_u);
    k5_scores<<<(BS * NA * (NC / 4) + 255) / 256, 256, 0, stream>>>(
        al_res, out_labels, out_fg, out_tgt,
        (const float*)pos_align_u, (const float*)pos_ov_u, out_scores);
}